// Round 11
// baseline (306.901 us; speedup 1.0000x reference)
//
#include <hip/hip_runtime.h>
#include <hip/hip_fp16.h>
#include <math.h>

#define L 4096
#define CDIM 256
#define DIN 512
#define DSTATE 16
#define DTR 16
#define BATCH 4

using f32x4  = __attribute__((ext_vector_type(4))) float;
using f32x2  = __attribute__((ext_vector_type(2))) float;
using f16x8  = __attribute__((ext_vector_type(8))) _Float16;

#define LOG2E 1.44269504088896f

#if __has_builtin(__builtin_amdgcn_exp2f)
#define EXP2(x) __builtin_amdgcn_exp2f(x)
#else
#define EXP2(x) __expf((x) * 0.69314718056f)
#endif

__device__ __forceinline__ float silu_f(float x) {
    return __fdividef(x, 1.f + __expf(-x));
}
__device__ __forceinline__ float softplus_fast(float x) {
    return (x > 20.f) ? x : __logf(1.f + __expf(x));
}
__device__ __forceinline__ unsigned pk2h(float a, float b) {
    __half2 h = __floats2half2_rn(a, b);
    return *reinterpret_cast<unsigned*>(&h);
}

// async global->LDS, 16B per lane, dest = wave-uniform base + lane*16
__device__ __forceinline__ void gload_lds16(const void* g, void* l) {
    __builtin_amdgcn_global_load_lds(
        (const __attribute__((address_space(1))) void*)g,
        (__attribute__((address_space(3))) void*)l, 16, 0, 0);
}

// LESSONS (measured, do not repeat):
//  - r1: lgkm-only barrier + depth-2 reg prefetch regressed (6.6->4.4 MfmaUtil).
//  - r4: GEMM1+GEMM2 fusion neutral (stall-bound; blocks x k-iters unchanged).
//  - r4: replacing 16 exp2 (trans pipe, hidden under VALU) with 15 serial VALU
//    muls REGRESSED scans ~+23us. Delete VALU ops, keep trans ops.
//  - r5: 128x128 tile regressed GEMMs: occupancy hides stalls here; 64-tile wins.
//  - r6: pk-f32 (f32x2) scan math WORKED: scans left the top-5. 320.1us.
//  - r7: infra flake; r8 resubmit passed.
//  - r8: gload_lds + LDK32 swizzle WORKED: GEMMs left top-5. 300.6us.
//  - r9: conv vectorization + AX->X,dsum traffic cut: small net (-3us). 297.7us.
//  - r10: NC 128->256 raised occupancy 25->36% but phase3 only 44.4->42.8:
//    scans NOT wave-starved -> LDS-read-pipe-bound (~12 ds_read_b128/t for
//    wave-UNIFORM B/C/dt = ~150 LDS cyc/t, the real floor).
//  - r11 theory: uniform data doesn't belong in LDS. Read B/C/dt from global
//    (uniform addr -> s_load SMEM pipe, or broadcast VMEM; both idle here).
//  - WRITE_SIZE on early dispatches includes harness memset traffic (artifact).

enum { HEPI_XP = 0, HEPI_UZ = 1, HEPI_F32 = 2, HEPI_D34 = 3 };

// ====== hgemm_g: 64-row tiles, global_load_lds staging, LDK=32 + XOR swizzle ======
template<int EPI, bool A_F32KM, int NT>
__global__ __launch_bounds__(256)
void hgemm_g(const float* __restrict__ Af0, const float* __restrict__ Af1,
             const __half* __restrict__ Ah_g, const __half* __restrict__ Bh_g,
             const float* __restrict__ bias,
             float* __restrict__ O0, __half* __restrict__ Oh0, __half* __restrict__ Oh1,
             int M, int N, int K, int kSplit, long strideAb, int nBlk)
{
    constexpr int BM = 64, MT = 2;
    constexpr int BN = 2 * NT * 16;         // 64 or 128
    constexpr int BCH = BN / 64;            // B gload instrs per wave: 1 or 2
    __shared__ __align__(16) _Float16 Ah[2][BM][32];
    __shared__ __align__(16) _Float16 Bh[2][BN][32];
    const int mBlk = M / BM;
    // XCD-sticky swizzle
    const int bid = blockIdx.x;
    const int r = bid & 7, q = bid >> 3;
    const int ni = q % nBlk;
    const int mg = (q / nBlk) * 8 + r;
    const int b = mg / mBlk, m_idx = mg - b * mBlk;
    const int n0 = ni * BN, m0 = m_idx * BM;
    const int tid  = threadIdx.x;
    const int lane = tid & 63;
    const int w    = tid >> 6;
    const int wr   = w >> 1, wc = w & 1;
    const int lrow = lane & 15;
    const int loct = lane >> 4;
    // gload source mapping: lane l -> row-in-chunk l>>2, swizzled k-octet kc
    const int gsub = lane >> 2;
    const int kc   = (lane & 3) ^ ((lane >> 3) & 3);
    // read-side swizzled column (f16 units), lane-constant
    const int swc  = (loct ^ ((lrow >> 1) & 3)) * 8;

    f32x4 acc[MT][NT];
    #pragma unroll
    for (int i = 0; i < MT; ++i)
        #pragma unroll
        for (int j = 0; j < NT; ++j)
            acc[i][j] = (f32x4){0.f, 0.f, 0.f, 0.f};

    float va[8];
    auto loadA32 = [&](int kk) {        // GEMM1: fp32 K-major A -> regs (needs cvt)
        if constexpr (A_F32KM) {
            int m = tid & 63, ks = tid >> 6;
            #pragma unroll
            for (int j = 0; j < 8; ++j) {
                int kg = kk + ks * 8 + j;
                const float* Ap; int kl;
                if (kg < kSplit) { Ap = Af0; kl = kg; } else { Ap = Af1; kl = kg - kSplit; }
                va[j] = Ap[(long)b * strideAb + (long)kl * M + m0 + m];
            }
        }
    };
    auto storeA32 = [&](int buf) {      // swizzled ds_write (matches read XOR)
        if constexpr (A_F32KM) {
            int m = tid & 63, ks = tid >> 6;
            int ksw = (ks ^ ((m >> 1) & 3)) * 8;
            uint4 h;
            h.x = pk2h(va[0], va[1]);
            h.y = pk2h(va[2], va[3]);
            h.z = pk2h(va[4], va[5]);
            h.w = pk2h(va[6], va[7]);
            *(uint4*)&Ah[buf][m][ksw] = h;
        }
    };
    auto stageA = [&](int kk, int buf) {
        if constexpr (!A_F32KM) {
            const __half* src = Ah_g + (long)b * strideAb +
                                (long)(m0 + w * 16 + gsub) * K + kk + kc * 8;
            gload_lds16(src, &Ah[buf][w * 16][0]);
        }
    };
    auto stageB = [&](int kk, int buf) {
        #pragma unroll
        for (int p = 0; p < BCH; ++p) {
            int ch = w * BCH + p;       // 16-row chunk index
            const __half* src = Bh_g + (long)(n0 + ch * 16 + gsub) * K + kk + kc * 8;
            gload_lds16(src, &Bh[buf][ch * 16][0]);
        }
    };

    loadA32(0);
    stageA(0, 0); stageB(0, 0);
    storeA32(0);
    __syncthreads();                    // drains vmcnt -> gloads landed
    int cur = 0;
    for (int kk = 0; kk < K; kk += 32) {
        const bool more = (kk + 32 < K);
        if (more) {
            loadA32(kk + 32);
            stageA(kk + 32, cur ^ 1);   // async, direct to LDS buf^1
            stageB(kk + 32, cur ^ 1);
        }
        f16x8 bh[NT];
        #pragma unroll
        for (int nt = 0; nt < NT; ++nt)
            bh[nt] = *(const f16x8*)&Bh[cur][wc*NT*16 + nt*16 + lrow][swc];
        #pragma unroll
        for (int mt = 0; mt < MT; ++mt) {
            f16x8 ah = *(const f16x8*)&Ah[cur][wr*MT*16 + mt*16 + lrow][swc];
            #pragma unroll
            for (int nt = 0; nt < NT; ++nt)
                acc[mt][nt] = __builtin_amdgcn_mfma_f32_16x16x32_f16(ah, bh[nt], acc[mt][nt], 0, 0, 0);
        }
        if (more) {
            storeA32(cur ^ 1);
            __syncthreads();            // ONE barrier per k-iter (r0 schedule)
            cur ^= 1;
        }
    }
    // epilogue: C/D col=lane&15, row=(lane>>4)*4+reg
    #pragma unroll
    for (int mt = 0; mt < MT; ++mt) {
        #pragma unroll
        for (int r4 = 0; r4 < 4; ++r4) {
            int m = m0 + wr*MT*16 + mt * 16 + loct * 4 + r4;
            long rowb = (long)b * M + m;
            #pragma unroll
            for (int nt = 0; nt < NT; ++nt) {
                int n = n0 + wc*NT*16 + nt * 16 + lrow;
                float v = acc[mt][nt][r4];
                if constexpr (EPI == HEPI_XP) {
                    Oh0[rowb * N + n] = __float2half(v + bias[n]);
                } else if constexpr (EPI == HEPI_UZ) {
                    if (n < DIN) Oh0[rowb * DIN + n] = __float2half(v);
                    else         Oh1[rowb * DIN + (n - DIN)] = __float2half(v);
                } else {
                    O0[rowb * N + n] = v;
                }
            }
        }
    }
}

#define LDK 40
// ====== old reg-staged hgemm (LDK=40): kept ONLY for D34 (needs OOB zero-guard) ===
template<int EPI, int NT>
__global__ __launch_bounds__(256)
void hgemm(const __half* __restrict__ Ah_g, const __half* __restrict__ Bh_g,
           float* __restrict__ O0, float* __restrict__ Ob, float* __restrict__ Oc,
           int M, int N, int K, long strideAb, int nBlk)
{
    constexpr int BM = 64, MT = 2;
    constexpr int BN = 2 * NT * 16;
    constexpr int BSEG = BN / 64;
    __shared__ __align__(16) _Float16 Ah[2][BM][LDK];
    __shared__ __align__(16) _Float16 Bh[2][BN][LDK];
    const int mBlk = M / BM;
    const int bid = blockIdx.x;
    const int r = bid & 7, q = bid >> 3;
    const int ni = q % nBlk;
    const int mg = (q / nBlk) * 8 + r;
    const int b = mg / mBlk, m_idx = mg - b * mBlk;
    const int n0 = ni * BN, m0 = m_idx * BM;
    const int tid  = threadIdx.x;
    const int lane = tid & 63;
    const int w    = tid >> 6;
    const int wr   = w >> 1, wc = w & 1;
    const int lrow = lane & 15;
    const int loct = lane >> 4;

    f32x4 acc[MT][NT];
    #pragma unroll
    for (int i = 0; i < MT; ++i)
        #pragma unroll
        for (int j = 0; j < NT; ++j)
            acc[i][j] = (f32x4){0.f, 0.f, 0.f, 0.f};

    const int sOct = tid & 3, sRow = tid >> 2;
    uint4 pa, pb[BSEG];

    auto loadA = [&](int kk) {
        pa = *(const uint4*)(Ah_g + (long)b * strideAb +
                             (long)(m0 + sRow) * K + kk + sOct * 8);
    };
    auto loadB = [&](int kk) {
        #pragma unroll
        for (int p = 0; p < BSEG; ++p) {
            int ng = n0 + sRow + p * 64;
            if (ng >= N) pb[p] = make_uint4(0, 0, 0, 0);
            else pb[p] = *(const uint4*)(Bh_g + (long)ng * K + kk + sOct * 8);
        }
    };
    auto storeAB = [&](int buf) {
        *(uint4*)&Ah[buf][sRow][sOct * 8] = pa;
        #pragma unroll
        for (int p = 0; p < BSEG; ++p)
            *(uint4*)&Bh[buf][sRow + p * 64][sOct * 8] = pb[p];
    };

    loadA(0); loadB(0);
    storeAB(0);
    __syncthreads();
    int cur = 0;
    for (int kk = 0; kk < K; kk += 32) {
        const bool more = (kk + 32 < K);
        if (more) { loadA(kk + 32); loadB(kk + 32); }
        f16x8 bh[NT];
        #pragma unroll
        for (int nt = 0; nt < NT; ++nt)
            bh[nt] = *(const f16x8*)&Bh[cur][wc*NT*16 + nt*16 + lrow][loct*8];
        #pragma unroll
        for (int mt = 0; mt < MT; ++mt) {
            f16x8 ah = *(const f16x8*)&Ah[cur][wr*MT*16 + mt*16 + lrow][loct*8];
            #pragma unroll
            for (int nt = 0; nt < NT; ++nt)
                acc[mt][nt] = __builtin_amdgcn_mfma_f32_16x16x32_f16(ah, bh[nt], acc[mt][nt], 0, 0, 0);
        }
        if (more) {
            storeAB(cur ^ 1);
            __syncthreads();
            cur ^= 1;
        }
    }
    #pragma unroll
    for (int mt = 0; mt < MT; ++mt) {
        #pragma unroll
        for (int r4 = 0; r4 < 4; ++r4) {
            int m = m0 + wr*MT*16 + mt * 16 + loct * 4 + r4;
            long rowb = (long)b * M + m;
            #pragma unroll
            for (int nt = 0; nt < NT; ++nt) {
                int n = n0 + wc*NT*16 + nt * 16 + lrow;
                float v = acc[mt][nt][r4];
                if (n < DTR)           O0[rowb * DTR + n] = v;
                else if (n < 2 * DTR)  Ob[rowb * 16 + (n - DTR)] = v;
                else if (n < 48)       Oc[rowb * 16 + (n - 32)] = v;
            }
        }
    }
}

// ---------------- weight prep: fp16 casts ---------
#define SZ_WP  131072
#define SZ_WIN 262144
#define SZ_WO  131072
#define SZ_WC  24576
__global__ __launch_bounds__(256)
void pack_all(const float* __restrict__ Wp, const float* __restrict__ Win,
              const float* __restrict__ Wout, const float* __restrict__ Wx,
              __half* __restrict__ wph, __half* __restrict__ winh,
              __half* __restrict__ woh, __half* __restrict__ wch)
{
    int i = blockIdx.x * 256 + threadIdx.x;
    if (i < SZ_WP) { wph[i] = __float2half(Wp[i]); return; }
    i -= SZ_WP;
    if (i < SZ_WIN) { winh[i] = __float2half(Win[i]); return; }
    i -= SZ_WIN;
    if (i < SZ_WO) { woh[i] = __float2half(Wout[i]); return; }
    i -= SZ_WO;
    if (i < SZ_WC) wch[i] = __float2half(Wx[i]);   // (48, 512) row-major
}

// ------- depthwise causal conv (k=4) + silu: VECTORIZED 8 d's/thread (G13) -------
__global__ __launch_bounds__(256)
void conv_silu_kernel(const __half* __restrict__ u_pre, const float* __restrict__ cw,
                      const float* __restrict__ cb, __half* __restrict__ u)
{
    long gid = (long)blockIdx.x * 256 + threadIdx.x;   // NLD/8 threads
    const int dv = (int)(gid & 63);                    // d0 = dv*8
    const long bl = gid >> 6;                          // b*L + l
    const int l = (int)(bl & (L - 1));
    const long brow = bl - l;
    const int d0 = dv * 8;

    float acc[8];
    {
        float4 c0 = *(const float4*)&cb[d0];
        float4 c1 = *(const float4*)&cb[d0 + 4];
        acc[0]=c0.x; acc[1]=c0.y; acc[2]=c0.z; acc[3]=c0.w;
        acc[4]=c1.x; acc[5]=c1.y; acc[6]=c1.z; acc[7]=c1.w;
    }
    float4 wrow[8];                                    // cw rows (hot 8KB in L2)
    #pragma unroll
    for (int e = 0; e < 8; ++e) wrow[e] = *(const float4*)&cw[(d0 + e) * 4];

    #pragma unroll
    for (int j = 0; j < 4; ++j) {
        int li = l - 3 + j;                            // wave-uniform branch
        if (li >= 0) {
            uint4 raw = *(const uint4*)(u_pre + (brow + li) * DIN + d0);
            const __half2* h2 = (const __half2*)&raw;
            #pragma unroll
            for (int e = 0; e < 4; ++e) {
                float2 f = __half22float2(h2[e]);
                float w0 = (j == 0) ? wrow[2*e].x : (j == 1) ? wrow[2*e].y
                         : (j == 2) ? wrow[2*e].z : wrow[2*e].w;
                float w1 = (j == 0) ? wrow[2*e+1].x : (j == 1) ? wrow[2*e+1].y
                         : (j == 2) ? wrow[2*e+1].z : wrow[2*e+1].w;
                acc[2*e]   = fmaf(f.x, w0, acc[2*e]);
                acc[2*e+1] = fmaf(f.y, w1, acc[2*e+1]);
            }
        }
    }
    uint4 st;
    st.x = pk2h(silu_f(acc[0]), silu_f(acc[1]));
    st.y = pk2h(silu_f(acc[2]), silu_f(acc[3]));
    st.z = pk2h(silu_f(acc[4]), silu_f(acc[5]));
    st.w = pk2h(silu_f(acc[6]), silu_f(acc[7]));
    *(uint4*)(u + bl * DIN + d0) = st;
}

// ---------------- chunked parallel selective scan, d-per-lane ----------------
// r11: B/C/dt are wave-UNIFORM per t -> read straight from global (uniform addr
// promotes to s_load on the idle SMEM pipe; worst case broadcast VMEM -- also
// idle). LDS keeps only the per-lane u/z tiles (2 ds_read/t instead of 14).
#define NC 256
#define LC (L / NC)

__device__ __forceinline__ f32x2 fma2(f32x2 a, f32x2 b, f32x2 c) {
    return __builtin_elementwise_fma(a, b, c);
}

__global__ __launch_bounds__(256)
void scan_phase1(const float* __restrict__ dtA, const __half* __restrict__ u,
                 const float* __restrict__ Bm, const float* __restrict__ A_log,
                 const float* __restrict__ Wdt, const float* __restrict__ bdt,
                 float* __restrict__ Xc, float* __restrict__ DS)
{
    __shared__ __half sU[LC][256];
    const int gd = blockIdx.x & 1;
    const int c  = (blockIdx.x >> 1) & (NC - 1);
    const int b  = blockIdx.x >> 9;
    const int tid = threadIdx.x;
    const int d  = gd * 256 + tid;
    const int t0 = c * LC;
    f32x2 A2[8];
    #pragma unroll
    for (int q = 0; q < 4; ++q) {
        float4 v = *(const float4*)&A_log[d * DSTATE + q * 4];
        A2[2*q]   = (f32x2){-__expf(v.x) * LOG2E, -__expf(v.y) * LOG2E};
        A2[2*q+1] = (f32x2){-__expf(v.z) * LOG2E, -__expf(v.w) * LOG2E};
    }
    f32x2 Wv[8];
    #pragma unroll
    for (int q = 0; q < 4; ++q) {
        float4 v = *(const float4*)&Wdt[d * DTR + q * 4];
        Wv[2*q]   = (f32x2){v.x, v.y};
        Wv[2*q+1] = (f32x2){v.z, v.w};
    }
    const float bd = bdt[d];
    {
        const __half* ub = u + ((long)b * L + t0) * DIN + gd * 256;
        #pragma unroll
        for (int j = 0; j < 2; ++j) {
            int i = tid + j * 256;            // 512 float4s = 16 rows x 32
            int t = i >> 5, col = (i & 31) * 8;
            *(float4*)&sU[t][col] = *(const float4*)&ub[(long)t * DIN + col];
        }
    }
    const float* __restrict__ Bt = Bm  + ((long)b * L + t0) * DSTATE;  // uniform
    const float* __restrict__ Dt = dtA + ((long)b * L + t0) * DTR;     // uniform
    __syncthreads();
    f32x2 X2[8];
    #pragma unroll
    for (int k = 0; k < 8; ++k) X2[k] = (f32x2){0.f, 0.f};
    float dsum = 0.f;
    #pragma unroll 2
    for (int t = 0; t < LC; ++t) {
        float qd[16], br[16];
        *(float4*)&qd[0]  = *(const float4*)&Dt[t * DTR + 0];
        *(float4*)&qd[4]  = *(const float4*)&Dt[t * DTR + 4];
        *(float4*)&qd[8]  = *(const float4*)&Dt[t * DTR + 8];
        *(float4*)&qd[12] = *(const float4*)&Dt[t * DTR + 12];
        f32x2 dpA = (f32x2){0.f, 0.f}, dpB = (f32x2){0.f, 0.f};
        #pragma unroll
        for (int k = 0; k < 8; k += 2) {
            dpA = fma2(*(const f32x2*)&qd[2*k],     Wv[k],     dpA);
            dpB = fma2(*(const f32x2*)&qd[2*k+2],   Wv[k+1],   dpB);
        }
        float dlt = softplus_fast(((dpA.x + dpA.y) + (dpB.x + dpB.y)) + bd);
        dsum += dlt;
        float du = dlt * __half2float(sU[t][tid]);
        f32x2 du2  = (f32x2){du, du};
        f32x2 dlt2 = (f32x2){dlt, dlt};
        *(float4*)&br[0]  = *(const float4*)&Bt[t * DSTATE + 0];
        *(float4*)&br[4]  = *(const float4*)&Bt[t * DSTATE + 4];
        *(float4*)&br[8]  = *(const float4*)&Bt[t * DSTATE + 8];
        *(float4*)&br[12] = *(const float4*)&Bt[t * DSTATE + 12];
        #pragma unroll
        for (int k = 0; k < 8; ++k) {
            f32x2 tt = dlt2 * A2[k];
            f32x2 a2;
            a2.x = EXP2(tt.x);
            a2.y = EXP2(tt.y);
            X2[k] = fma2(a2, X2[k], du2 * *(const f32x2*)&br[2*k]);
        }
    }
    long o = (((long)b * NC + c) * DIN + d) * DSTATE;
    #pragma unroll
    for (int q = 0; q < 4; ++q)
        *(float4*)&Xc[o + q * 4] =
            make_float4(X2[2*q].x, X2[2*q].y, X2[2*q+1].x, X2[2*q+1].y);
    DS[((long)b * NC + c) * DIN + d] = dsum;
}

// cross-chunk scan: 32768 independent series; pure-ILP kernel.
// 8-chunk groups, depth-2 prefetch (16 loads/type in flight).
__global__ __launch_bounds__(256)
void scan_phase2(const float* __restrict__ Xc, const float* __restrict__ DS,
                 const float* __restrict__ A_log, float* __restrict__ Hout)
{
    int lane = blockIdx.x * 256 + threadIdx.x;   // 32768 total
    int b = lane >> 13;
    int rem = lane & 8191;                       // d*16 + s
    int d = rem >> 4;
    const float Ar = -__expf(A_log[rem]) * LOG2E;
    const long cs = (long)DIN * DSTATE;
    const long xb = (long)b * NC * cs + rem;
    const long db = (long)b * NC * DIN + d;
    float h = 0.f;
    float xc_[8], ts_[8], nx_[8], nt_[8];
    auto ldx = [&](int c) { return Xc[xb + (long)c * cs]; };
    auto ldt = [&](int c) { return DS[db + (long)c * DIN]; };
    #pragma unroll
    for (int j = 0; j < 8; ++j) { xc_[j] = ldx(j);     ts_[j] = ldt(j); }
    #pragma unroll
    for (int j = 0; j < 8; ++j) { nx_[j] = ldx(8 + j); nt_[j] = ldt(8 + j); }
    for (int c = 0; c < NC; c += 8) {
        #pragma unroll
        for (int j = 0; j < 8; ++j) {
            Hout[xb + (long)(c + j) * cs] = h;
            h = fmaf(EXP2(ts_[j] * Ar), h, xc_[j]);
        }
        #pragma unroll
        for (int j = 0; j < 8; ++j) { xc_[j] = nx_[j]; ts_[j] = nt_[j]; }
        if (c + 16 < NC) {
            #pragma unroll
            for (int j = 0; j < 8; ++j) {
                nx_[j] = ldx(c + 16 + j);
                nt_[j] = ldt(c + 16 + j);
            }
        }
    }
}

__global__ __launch_bounds__(256)
void scan_phase3(const float* __restrict__ dtA, const __half* __restrict__ u,
                 const float* __restrict__ Bm, const float* __restrict__ Cm,
                 const __half* __restrict__ z, const float* __restrict__ A_log,
                 const float* __restrict__ Wdt, const float* __restrict__ bdt,
                 const float* __restrict__ Dp, const float* __restrict__ Hinit,
                 __half* __restrict__ y2h)
{
    __shared__ __half sU[LC][256];
    __shared__ __half sZ[LC][256];
    const int gd = blockIdx.x & 1;
    const int c  = (blockIdx.x >> 1) & (NC - 1);
    const int b  = blockIdx.x >> 9;
    const int tid = threadIdx.x;
    const int d  = gd * 256 + tid;
    const int t0 = c * LC;
    f32x2 A2[8];
    #pragma unroll
    for (int q = 0; q < 4; ++q) {
        float4 v = *(const float4*)&A_log[d * DSTATE + q * 4];
        A2[2*q]   = (f32x2){-__expf(v.x) * LOG2E, -__expf(v.y) * LOG2E};
        A2[2*q+1] = (f32x2){-__expf(v.z) * LOG2E, -__expf(v.w) * LOG2E};
    }
    f32x2 Wv[8];
    #pragma unroll
    for (int q = 0; q < 4; ++q) {
        float4 v = *(const float4*)&Wdt[d * DTR + q * 4];
        Wv[2*q]   = (f32x2){v.x, v.y};
        Wv[2*q+1] = (f32x2){v.z, v.w};
    }
    const float bd = bdt[d];
    {
        const __half* ub = u + ((long)b * L + t0) * DIN + gd * 256;
        const __half* zb = z + ((long)b * L + t0) * DIN + gd * 256;
        #pragma unroll
        for (int j = 0; j < 2; ++j) {
            int i = tid + j * 256;
            int t = i >> 5, col = (i & 31) * 8;
            *(float4*)&sU[t][col] = *(const float4*)&ub[(long)t * DIN + col];
            *(float4*)&sZ[t][col] = *(const float4*)&zb[(long)t * DIN + col];
        }
    }
    const float* __restrict__ Bt = Bm  + ((long)b * L + t0) * DSTATE;  // uniform
    const float* __restrict__ Ct = Cm  + ((long)b * L + t0) * DSTATE;  // uniform
    const float* __restrict__ Dt = dtA + ((long)b * L + t0) * DTR;     // uniform
    f32x2 h2[8];
    {
        long o = (((long)b * NC + c) * DIN + d) * DSTATE;
        #pragma unroll
        for (int q = 0; q < 4; ++q) {
            float4 v = *(const float4*)&Hinit[o + q * 4];
            h2[2*q]   = (f32x2){v.x, v.y};
            h2[2*q+1] = (f32x2){v.z, v.w};
        }
    }
    const float Dval = Dp[d];
    const long gbase = ((long)b * L + t0) * DIN + d;
    __syncthreads();
    #pragma unroll 2
    for (int t = 0; t < LC; ++t) {
        float qd[16], br[16], cr[16];
        *(float4*)&qd[0]  = *(const float4*)&Dt[t * DTR + 0];
        *(float4*)&qd[4]  = *(const float4*)&Dt[t * DTR + 4];
        *(float4*)&qd[8]  = *(const float4*)&Dt[t * DTR + 8];
        *(float4*)&qd[12] = *(const float4*)&Dt[t * DTR + 12];
        f32x2 dpA = (f32x2){0.f, 0.f}, dpB = (f32x2){0.f, 0.f};
        #pragma unroll
        for (int k = 0; k < 8; k += 2) {
            dpA = fma2(*(const f32x2*)&qd[2*k],   Wv[k],   dpA);
            dpB = fma2(*(const f32x2*)&qd[2*k+2], Wv[k+1], dpB);
        }
        float dlt = softplus_fast(((dpA.x + dpA.y) + (dpB.x + dpB.y)) + bd);
        float uu = __half2float(sU[t][tid]);
        float zz = __half2float(sZ[t][tid]);
        float du = dlt * uu;
        f32x2 du2  = (f32x2){du, du};
        f32x2 dlt2 = (f32x2){dlt, dlt};
        *(float4*)&br[0]  = *(const float4*)&Bt[t * DSTATE + 0];
        *(float4*)&br[4]  = *(const float4*)&Bt[t * DSTATE + 4];
        *(float4*)&br[8]  = *(const float4*)&Bt[t * DSTATE + 8];
        *(float4*)&br[12] = *(const float4*)&Bt[t * DSTATE + 12];
        *(float4*)&cr[0]  = *(const float4*)&Ct[t * DSTATE + 0];
        *(float4*)&cr[4]  = *(const float4*)&Ct[t * DSTATE + 4];
        *(float4*)&cr[8]  = *(const float4*)&Ct[t * DSTATE + 8];
        *(float4*)&cr[12] = *(const float4*)&Ct[t * DSTATE + 12];
        f32x2 y2a = (f32x2){0.f, 0.f}, y2b = (f32x2){0.f, 0.f};
        f32x2 y2c = (f32x2){0.f, 0.f}, y2d = (f32x2){0.f, 0.f};
        #pragma unroll
        for (int k = 0; k < 8; k += 4) {
            f32x2 t0v = dlt2 * A2[k+0];
            f32x2 t1v = dlt2 * A2[k+1];
            f32x2 t2v = dlt2 * A2[k+2];
            f32x2 t3v = dlt2 * A2[k+3];
            f32x2 a0, a1, a2v, a3;
            a0.x = EXP2(t0v.x); a0.y = EXP2(t0v.y);
            a1.x = EXP2(t1v.x); a1.y = EXP2(t1v.y);
            a2v.x = EXP2(t2v.x); a2v.y = EXP2(t2v.y);
            a3.x = EXP2(t3v.x); a3.y = EXP2(t3v.y);
            h2[k+0] = fma2(h2[k+0], a0,  du2 * *(const f32x2*)&br[2*k+0]);
            h2[k+1] = fma2(h2[k+1], a1,  du2 * *(const f32x2*)&br[2*k+2]);
            h2[k+2] = fma2(h2[k+2], a2v, du2 * *(const f32x2*)&br[2*k+4]);
            h2[k+3] = fma2(h2[k+3], a3,  du2 * *(const f32x2*)&br[2*k+6]);
            y2a = fma2(h2[k+0], *(const f32x2*)&cr[2*k+0], y2a);
            y2b = fma2(h2[k+1], *(const f32x2*)&cr[2*k+2], y2b);
            y2c = fma2(h2[k+2], *(const f32x2*)&cr[2*k+4], y2c);
            y2d = fma2(h2[k+3], *(const f32x2*)&cr[2*k+6], y2d);
        }
        f32x2 ys = (y2a + y2b) + (y2c + y2d);
        float y = ys.x + ys.y;
        y2h[gbase + t * DIN] = __float2half((y + uu * Dval) * silu_f(zz));
    }
}

// ---------------- LayerNorm over C + transpose to (B,C,L) ----------------
__global__ __launch_bounds__(256)
void ln_kernel(const float* __restrict__ X, const float* __restrict__ gamma,
               const float* __restrict__ beta, float* __restrict__ out)
{
    __shared__ float tile[32][257];
    __shared__ float sMu[32], sRs[32];
    const int l0 = blockIdx.x * 32;
    const int b  = blockIdx.y;
    const int tid = threadIdx.x;
    for (int i = tid; i < 32 * 256; i += 256) {
        int l = i >> 8, c = i & 255;
        tile[l][c] = X[((long)b * L + l0 + l) * CDIM + c];
    }
    __syncthreads();
    {
        int l = tid >> 3, sub = tid & 7;
        float s1 = 0.f, s2 = 0.f;
        for (int c = sub * 32; c < sub * 32 + 32; ++c) {
            float v = tile[l][c];
            s1 += v; s2 += v * v;
        }
        s1 += __shfl_xor(s1, 1); s2 += __shfl_xor(s2, 1);
        s1 += __shfl_xor(s1, 2); s2 += __shfl_xor(s2, 2);
        s1 += __shfl_xor(s1, 4); s2 += __shfl_xor(s2, 4);
        if (sub == 0) {
            float mu = s1 * (1.f / 256.f);
            float var = s2 * (1.f / 256.f) - mu * mu;
            sMu[l] = mu;
            sRs[l] = rsqrtf(var + 1e-5f);
        }
    }
    __syncthreads();
    for (int i = tid; i < 32 * 256; i += 256) {
        int ll = i & 31, c = i >> 5;
        float v = (tile[ll][c] - sMu[ll]) * sRs[ll] * gamma[c] + beta[c];
        out[((long)b * CDIM + c) * L + l0 + ll] = v;
    }
}

extern "C" void kernel_launch(void* const* d_in, const int* in_sizes, int n_in,
                              void* d_out, int out_size, void* d_ws, size_t ws_size,
                              hipStream_t stream)
{
    const float* sp   = (const float*)d_in[0];
    const float* fq   = (const float*)d_in[1];
    const float* Wp   = (const float*)d_in[2];
    const float* bp   = (const float*)d_in[3];
    const float* Win  = (const float*)d_in[4];
    const float* cw   = (const float*)d_in[5];
    const float* cb   = (const float*)d_in[6];
    const float* Wx   = (const float*)d_in[7];
    const float* Wdt  = (const float*)d_in[8];
    const float* bdt  = (const float*)d_in[9];
    const float* Alog = (const float*)d_in[10];
    const float* Dp   = (const float*)d_in[11];
    const float* Wout = (const float*)d_in[12];
    const float* gam  = (const float*)d_in[13];
    const float* bet  = (const float*)d_in[14];
    float* out = (float*)d_out;
    float* ws  = (float*)d_ws;

    const size_t NLD = (size_t)BATCH * L * DIN;   // 8.39M
    const size_t NLC = (size_t)BATCH * L * CDIM;  // 4.19M

    size_t off = 0;
    __half* u16   = (__half*)(ws + off); off += NLD / 2;  // pre-conv u
    __half* u16c  = (__half*)(ws + off); off += NLD / 2;  // post-conv silu(u)
    __half* z16   = (__half*)(ws + off); off += NLD / 2;
    __half* y16   = (__half*)(ws + off); off += NLD / 2;
    __half* xp16  = (__half*)(ws + off); off += NLC / 2;
    float*  xmix  = ws + off; off += NLC;
    float*  dtA   = ws + off; off += (size_t)BATCH * L * DTR;
    __half* wph   = (__half*)(ws + off); off += SZ_WP / 2;
    __half* winh  = (__half*)(ws + off); off += SZ_WIN / 2;
    __half* woh   = (__half*)(ws + off); off += SZ_WO / 2;
    __half* wch   = (__half*)(ws + off); off += SZ_WC / 2;
    float*  Bmb   = ws + off; off += (size_t)BATCH * L * DSTATE;
    float*  Cmb   = ws + off; off += (size_t)BATCH * L * DSTATE;
    float*  Xc    = ws + off; off += (size_t)BATCH * NC * DIN * DSTATE;
    float*  DS    = ws + off; off += (size_t)BATCH * NC * DIN;
    float*  Hout  = ws + off; off += (size_t)BATCH * NC * DIN * DSTATE;

    dim3 blk(256);
    pack_all<<<dim3((SZ_WP + SZ_WIN + SZ_WO + SZ_WC) / 256), blk, 0, stream>>>(
        Wp, Win, Wout, Wx, wph, winh, woh, wch);

    // GEMM1: x_proj = x_cat @ Wp^T + bp  (A fp32 K-major reg-staged; B gload_lds)
    hgemm_g<HEPI_XP, true, 2><<<dim3(BATCH * (L/64) * 4), blk, 0, stream>>>(
        sp, fq, nullptr, wph, bp, nullptr, xp16, nullptr,
        L, CDIM, 2 * CDIM, CDIM, (long)CDIM * L, 4);
    // GEMM2: xz = x_proj @ Win^T -> u16 / z16  (full gload_lds staging)
    hgemm_g<HEPI_UZ, false, 4><<<dim3(BATCH * (L/64) * 8), blk, 0, stream>>>(
        nullptr, nullptr, xp16, winh, nullptr, nullptr, u16, z16,
        L, 2 * DIN, CDIM, 1 << 30, (long)L * CDIM, 8);

    conv_silu_kernel<<<dim3((int)(NLD / 8 / 256)), blk, 0, stream>>>(u16, cw, cb, u16c);
    // D34 rank-16: dbc = u @ Wx^T (N=48: dt|Bm|Cm) -- old kernel (OOB guard)
    hgemm<HEPI_D34, 2><<<dim3(BATCH * (L/64) * 1), blk, 0, stream>>>(
        u16c, wch, dtA, Bmb, Cmb, L, 48, DIN, (long)L * DIN, 1);

    scan_phase1<<<dim3(BATCH * NC * 2), blk, 0, stream>>>(
        dtA, u16c, Bmb, Alog, Wdt, bdt, Xc, DS);
    scan_phase2<<<dim3(BATCH * DIN * DSTATE / 256), blk, 0, stream>>>(Xc, DS, Alog, Hout);
    scan_phase3<<<dim3(BATCH * NC * 2), blk, 0, stream>>>(
        dtA, u16c, Bmb, Cmb, z16, Alog, Wdt, bdt, Dp, Hout, y16);

    // GEMM5: x_mixed = y2 @ Wout^T  (full gload_lds staging)
    hgemm_g<HEPI_F32, false, 2><<<dim3(BATCH * (L/64) * 4), blk, 0, stream>>>(
        nullptr, nullptr, y16, woh, nullptr, xmix, nullptr, nullptr,
        L, CDIM, DIN, 1 << 30, (long)L * DIN, 4);
    ln_kernel<<<dim3(L / 32, BATCH), blk, 0, stream>>>(xmix, gam, bet, out);
}

// Round 12
// 297.729 us; speedup vs baseline: 1.0308x; 1.0308x over previous
//
#include <hip/hip_runtime.h>
#include <hip/hip_fp16.h>
#include <math.h>

#define L 4096
#define CDIM 256
#define DIN 512
#define DSTATE 16
#define DTR 16
#define BATCH 4

using f32x4  = __attribute__((ext_vector_type(4))) float;
using f32x2  = __attribute__((ext_vector_type(2))) float;
using f16x8  = __attribute__((ext_vector_type(8))) _Float16;

#define LOG2E 1.44269504088896f

#if __has_builtin(__builtin_amdgcn_exp2f)
#define EXP2(x) __builtin_amdgcn_exp2f(x)
#else
#define EXP2(x) __expf((x) * 0.69314718056f)
#endif

__device__ __forceinline__ float silu_f(float x) {
    return __fdividef(x, 1.f + __expf(-x));
}
__device__ __forceinline__ float softplus_fast(float x) {
    return (x > 20.f) ? x : __logf(1.f + __expf(x));
}
__device__ __forceinline__ unsigned pk2h(float a, float b) {
    __half2 h = __floats2half2_rn(a, b);
    return *reinterpret_cast<unsigned*>(&h);
}

// async global->LDS, 16B per lane, dest = wave-uniform base + lane*16
__device__ __forceinline__ void gload_lds16(const void* g, void* l) {
    __builtin_amdgcn_global_load_lds(
        (const __attribute__((address_space(1))) void*)g,
        (__attribute__((address_space(3))) void*)l, 16, 0, 0);
}

// LESSONS (measured, do not repeat):
//  - r1: lgkm-only barrier + depth-2 reg prefetch regressed (6.6->4.4 MfmaUtil).
//  - r4: GEMM1+GEMM2 fusion neutral (stall-bound; blocks x k-iters unchanged).
//  - r4: replacing 16 exp2 (trans, hidden under VALU) with serial VALU muls
//    REGRESSED scans ~+23us. Delete VALU ops, keep trans ops.
//  - r5: 128x128 tile regressed GEMMs: occupancy hides stalls; 64-tile wins.
//  - r6: pk-f32 (f32x2) scan math WORKED (-15%): scans briefly left top-5.
//  - r8: gload_lds + LDK32 swizzle WORKED: GEMMs left top-5. 300.6us.
//  - r9: conv vectorization + traffic cut: small net. 297.7us (best).
//  - r10: occupancy x2 -> phase3 only +4%. NOT wave-starved.
//  - r11: deleting 12/14 LDS reads -> phase3 UNCHANGED. NOT LDS-pipe-bound.
//    => scans are bound by the issued instruction stream + dlt dependency.
//    Only deleting issued work has ever moved them (r6). r12: delete the
//    duplicated dp-dot+softplus from phase3 via fp32 delta handoff (bit-exact).
//  - WRITE_SIZE on early dispatches includes harness memset traffic (artifact).

enum { HEPI_XP = 0, HEPI_UZ = 1, HEPI_F32 = 2, HEPI_D34 = 3 };

// ====== hgemm_g: 64-row tiles, global_load_lds staging, LDK=32 + XOR swizzle ======
template<int EPI, bool A_F32KM, int NT>
__global__ __launch_bounds__(256)
void hgemm_g(const float* __restrict__ Af0, const float* __restrict__ Af1,
             const __half* __restrict__ Ah_g, const __half* __restrict__ Bh_g,
             const float* __restrict__ bias,
             float* __restrict__ O0, __half* __restrict__ Oh0, __half* __restrict__ Oh1,
             int M, int N, int K, int kSplit, long strideAb, int nBlk)
{
    constexpr int BM = 64, MT = 2;
    constexpr int BN = 2 * NT * 16;         // 64 or 128
    constexpr int BCH = BN / 64;            // B gload instrs per wave: 1 or 2
    __shared__ __align__(16) _Float16 Ah[2][BM][32];
    __shared__ __align__(16) _Float16 Bh[2][BN][32];
    const int mBlk = M / BM;
    // XCD-sticky swizzle
    const int bid = blockIdx.x;
    const int r = bid & 7, q = bid >> 3;
    const int ni = q % nBlk;
    const int mg = (q / nBlk) * 8 + r;
    const int b = mg / mBlk, m_idx = mg - b * mBlk;
    const int n0 = ni * BN, m0 = m_idx * BM;
    const int tid  = threadIdx.x;
    const int lane = tid & 63;
    const int w    = tid >> 6;
    const int wr   = w >> 1, wc = w & 1;
    const int lrow = lane & 15;
    const int loct = lane >> 4;
    // gload source mapping: lane l -> row-in-chunk l>>2, swizzled k-octet kc
    const int gsub = lane >> 2;
    const int kc   = (lane & 3) ^ ((lane >> 3) & 3);
    // read-side swizzled column (f16 units), lane-constant
    const int swc  = (loct ^ ((lrow >> 1) & 3)) * 8;

    f32x4 acc[MT][NT];
    #pragma unroll
    for (int i = 0; i < MT; ++i)
        #pragma unroll
        for (int j = 0; j < NT; ++j)
            acc[i][j] = (f32x4){0.f, 0.f, 0.f, 0.f};

    float va[8];
    auto loadA32 = [&](int kk) {        // GEMM1: fp32 K-major A -> regs (needs cvt)
        if constexpr (A_F32KM) {
            int m = tid & 63, ks = tid >> 6;
            #pragma unroll
            for (int j = 0; j < 8; ++j) {
                int kg = kk + ks * 8 + j;
                const float* Ap; int kl;
                if (kg < kSplit) { Ap = Af0; kl = kg; } else { Ap = Af1; kl = kg - kSplit; }
                va[j] = Ap[(long)b * strideAb + (long)kl * M + m0 + m];
            }
        }
    };
    auto storeA32 = [&](int buf) {      // swizzled ds_write (matches read XOR)
        if constexpr (A_F32KM) {
            int m = tid & 63, ks = tid >> 6;
            int ksw = (ks ^ ((m >> 1) & 3)) * 8;
            uint4 h;
            h.x = pk2h(va[0], va[1]);
            h.y = pk2h(va[2], va[3]);
            h.z = pk2h(va[4], va[5]);
            h.w = pk2h(va[6], va[7]);
            *(uint4*)&Ah[buf][m][ksw] = h;
        }
    };
    auto stageA = [&](int kk, int buf) {
        if constexpr (!A_F32KM) {
            const __half* src = Ah_g + (long)b * strideAb +
                                (long)(m0 + w * 16 + gsub) * K + kk + kc * 8;
            gload_lds16(src, &Ah[buf][w * 16][0]);
        }
    };
    auto stageB = [&](int kk, int buf) {
        #pragma unroll
        for (int p = 0; p < BCH; ++p) {
            int ch = w * BCH + p;       // 16-row chunk index
            const __half* src = Bh_g + (long)(n0 + ch * 16 + gsub) * K + kk + kc * 8;
            gload_lds16(src, &Bh[buf][ch * 16][0]);
        }
    };

    loadA32(0);
    stageA(0, 0); stageB(0, 0);
    storeA32(0);
    __syncthreads();                    // drains vmcnt -> gloads landed
    int cur = 0;
    for (int kk = 0; kk < K; kk += 32) {
        const bool more = (kk + 32 < K);
        if (more) {
            loadA32(kk + 32);
            stageA(kk + 32, cur ^ 1);   // async, direct to LDS buf^1
            stageB(kk + 32, cur ^ 1);
        }
        f16x8 bh[NT];
        #pragma unroll
        for (int nt = 0; nt < NT; ++nt)
            bh[nt] = *(const f16x8*)&Bh[cur][wc*NT*16 + nt*16 + lrow][swc];
        #pragma unroll
        for (int mt = 0; mt < MT; ++mt) {
            f16x8 ah = *(const f16x8*)&Ah[cur][wr*MT*16 + mt*16 + lrow][swc];
            #pragma unroll
            for (int nt = 0; nt < NT; ++nt)
                acc[mt][nt] = __builtin_amdgcn_mfma_f32_16x16x32_f16(ah, bh[nt], acc[mt][nt], 0, 0, 0);
        }
        if (more) {
            storeA32(cur ^ 1);
            __syncthreads();            // ONE barrier per k-iter (r0 schedule)
            cur ^= 1;
        }
    }
    // epilogue: C/D col=lane&15, row=(lane>>4)*4+reg
    #pragma unroll
    for (int mt = 0; mt < MT; ++mt) {
        #pragma unroll
        for (int r4 = 0; r4 < 4; ++r4) {
            int m = m0 + wr*MT*16 + mt * 16 + loct * 4 + r4;
            long rowb = (long)b * M + m;
            #pragma unroll
            for (int nt = 0; nt < NT; ++nt) {
                int n = n0 + wc*NT*16 + nt * 16 + lrow;
                float v = acc[mt][nt][r4];
                if constexpr (EPI == HEPI_XP) {
                    Oh0[rowb * N + n] = __float2half(v + bias[n]);
                } else if constexpr (EPI == HEPI_UZ) {
                    if (n < DIN) Oh0[rowb * DIN + n] = __float2half(v);
                    else         Oh1[rowb * DIN + (n - DIN)] = __float2half(v);
                } else {
                    O0[rowb * N + n] = v;
                }
            }
        }
    }
}

#define LDK 40
// ====== old reg-staged hgemm (LDK=40): kept ONLY for D34 (needs OOB zero-guard) ===
template<int EPI, int NT>
__global__ __launch_bounds__(256)
void hgemm(const __half* __restrict__ Ah_g, const __half* __restrict__ Bh_g,
           float* __restrict__ O0, float* __restrict__ Ob, float* __restrict__ Oc,
           int M, int N, int K, long strideAb, int nBlk)
{
    constexpr int BM = 64, MT = 2;
    constexpr int BN = 2 * NT * 16;
    constexpr int BSEG = BN / 64;
    __shared__ __align__(16) _Float16 Ah[2][BM][LDK];
    __shared__ __align__(16) _Float16 Bh[2][BN][LDK];
    const int mBlk = M / BM;
    const int bid = blockIdx.x;
    const int r = bid & 7, q = bid >> 3;
    const int ni = q % nBlk;
    const int mg = (q / nBlk) * 8 + r;
    const int b = mg / mBlk, m_idx = mg - b * mBlk;
    const int n0 = ni * BN, m0 = m_idx * BM;
    const int tid  = threadIdx.x;
    const int lane = tid & 63;
    const int w    = tid >> 6;
    const int wr   = w >> 1, wc = w & 1;
    const int lrow = lane & 15;
    const int loct = lane >> 4;

    f32x4 acc[MT][NT];
    #pragma unroll
    for (int i = 0; i < MT; ++i)
        #pragma unroll
        for (int j = 0; j < NT; ++j)
            acc[i][j] = (f32x4){0.f, 0.f, 0.f, 0.f};

    const int sOct = tid & 3, sRow = tid >> 2;
    uint4 pa, pb[BSEG];

    auto loadA = [&](int kk) {
        pa = *(const uint4*)(Ah_g + (long)b * strideAb +
                             (long)(m0 + sRow) * K + kk + sOct * 8);
    };
    auto loadB = [&](int kk) {
        #pragma unroll
        for (int p = 0; p < BSEG; ++p) {
            int ng = n0 + sRow + p * 64;
            if (ng >= N) pb[p] = make_uint4(0, 0, 0, 0);
            else pb[p] = *(const uint4*)(Bh_g + (long)ng * K + kk + sOct * 8);
        }
    };
    auto storeAB = [&](int buf) {
        *(uint4*)&Ah[buf][sRow][sOct * 8] = pa;
        #pragma unroll
        for (int p = 0; p < BSEG; ++p)
            *(uint4*)&Bh[buf][sRow + p * 64][sOct * 8] = pb[p];
    };

    loadA(0); loadB(0);
    storeAB(0);
    __syncthreads();
    int cur = 0;
    for (int kk = 0; kk < K; kk += 32) {
        const bool more = (kk + 32 < K);
        if (more) { loadA(kk + 32); loadB(kk + 32); }
        f16x8 bh[NT];
        #pragma unroll
        for (int nt = 0; nt < NT; ++nt)
            bh[nt] = *(const f16x8*)&Bh[cur][wc*NT*16 + nt*16 + lrow][loct*8];
        #pragma unroll
        for (int mt = 0; mt < MT; ++mt) {
            f16x8 ah = *(const f16x8*)&Ah[cur][wr*MT*16 + mt*16 + lrow][loct*8];
            #pragma unroll
            for (int nt = 0; nt < NT; ++nt)
                acc[mt][nt] = __builtin_amdgcn_mfma_f32_16x16x32_f16(ah, bh[nt], acc[mt][nt], 0, 0, 0);
        }
        if (more) {
            storeAB(cur ^ 1);
            __syncthreads();
            cur ^= 1;
        }
    }
    #pragma unroll
    for (int mt = 0; mt < MT; ++mt) {
        #pragma unroll
        for (int r4 = 0; r4 < 4; ++r4) {
            int m = m0 + wr*MT*16 + mt * 16 + loct * 4 + r4;
            long rowb = (long)b * M + m;
            #pragma unroll
            for (int nt = 0; nt < NT; ++nt) {
                int n = n0 + wc*NT*16 + nt * 16 + lrow;
                float v = acc[mt][nt][r4];
                if (n < DTR)           O0[rowb * DTR + n] = v;
                else if (n < 2 * DTR)  Ob[rowb * 16 + (n - DTR)] = v;
                else if (n < 48)       Oc[rowb * 16 + (n - 32)] = v;
            }
        }
    }
}

// ---------------- weight prep: fp16 casts ---------
#define SZ_WP  131072
#define SZ_WIN 262144
#define SZ_WO  131072
#define SZ_WC  24576
__global__ __launch_bounds__(256)
void pack_all(const float* __restrict__ Wp, const float* __restrict__ Win,
              const float* __restrict__ Wout, const float* __restrict__ Wx,
              __half* __restrict__ wph, __half* __restrict__ winh,
              __half* __restrict__ woh, __half* __restrict__ wch)
{
    int i = blockIdx.x * 256 + threadIdx.x;
    if (i < SZ_WP) { wph[i] = __float2half(Wp[i]); return; }
    i -= SZ_WP;
    if (i < SZ_WIN) { winh[i] = __float2half(Win[i]); return; }
    i -= SZ_WIN;
    if (i < SZ_WO) { woh[i] = __float2half(Wout[i]); return; }
    i -= SZ_WO;
    if (i < SZ_WC) wch[i] = __float2half(Wx[i]);   // (48, 512) row-major
}

// ------- depthwise causal conv (k=4) + silu: VECTORIZED 8 d's/thread (G13) -------
__global__ __launch_bounds__(256)
void conv_silu_kernel(const __half* __restrict__ u_pre, const float* __restrict__ cw,
                      const float* __restrict__ cb, __half* __restrict__ u)
{
    long gid = (long)blockIdx.x * 256 + threadIdx.x;   // NLD/8 threads
    const int dv = (int)(gid & 63);                    // d0 = dv*8
    const long bl = gid >> 6;                          // b*L + l
    const int l = (int)(bl & (L - 1));
    const long brow = bl - l;
    const int d0 = dv * 8;

    float acc[8];
    {
        float4 c0 = *(const float4*)&cb[d0];
        float4 c1 = *(const float4*)&cb[d0 + 4];
        acc[0]=c0.x; acc[1]=c0.y; acc[2]=c0.z; acc[3]=c0.w;
        acc[4]=c1.x; acc[5]=c1.y; acc[6]=c1.z; acc[7]=c1.w;
    }
    float4 wrow[8];                                    // cw rows (hot 8KB in L2)
    #pragma unroll
    for (int e = 0; e < 8; ++e) wrow[e] = *(const float4*)&cw[(d0 + e) * 4];

    #pragma unroll
    for (int j = 0; j < 4; ++j) {
        int li = l - 3 + j;                            // wave-uniform branch
        if (li >= 0) {
            uint4 raw = *(const uint4*)(u_pre + (brow + li) * DIN + d0);
            const __half2* h2 = (const __half2*)&raw;
            #pragma unroll
            for (int e = 0; e < 4; ++e) {
                float2 f = __half22float2(h2[e]);
                float w0 = (j == 0) ? wrow[2*e].x : (j == 1) ? wrow[2*e].y
                         : (j == 2) ? wrow[2*e].z : wrow[2*e].w;
                float w1 = (j == 0) ? wrow[2*e+1].x : (j == 1) ? wrow[2*e+1].y
                         : (j == 2) ? wrow[2*e+1].z : wrow[2*e+1].w;
                acc[2*e]   = fmaf(f.x, w0, acc[2*e]);
                acc[2*e+1] = fmaf(f.y, w1, acc[2*e+1]);
            }
        }
    }
    uint4 st;
    st.x = pk2h(silu_f(acc[0]), silu_f(acc[1]));
    st.y = pk2h(silu_f(acc[2]), silu_f(acc[3]));
    st.z = pk2h(silu_f(acc[4]), silu_f(acc[5]));
    st.w = pk2h(silu_f(acc[6]), silu_f(acc[7]));
    *(uint4*)(u + bl * DIN + d0) = st;
}

// ---------------- chunked parallel selective scan, d-per-lane ----------------
// r12: phase1 stores fp32 delta (bit-exact handoff); phase3 stages it in LDS and
// DELETES the duplicated dp-dot + softplus (~20 VALU + 2 trans + 4 LDS reads/t).
#define NC 256
#define LC (L / NC)

__device__ __forceinline__ f32x2 fma2(f32x2 a, f32x2 b, f32x2 c) {
    return __builtin_elementwise_fma(a, b, c);
}

__global__ __launch_bounds__(256)
void scan_phase1(const float* __restrict__ dtA, const __half* __restrict__ u,
                 const float* __restrict__ Bm, const float* __restrict__ A_log,
                 const float* __restrict__ Wdt, const float* __restrict__ bdt,
                 float* __restrict__ Xc, float* __restrict__ DS,
                 float* __restrict__ Dl)
{
    __shared__ float sB[LC][DSTATE];
    __shared__ float sDt[LC][DTR];
    __shared__ __half sU[LC][256];
    const int gd = blockIdx.x & 1;
    const int c  = (blockIdx.x >> 1) & (NC - 1);
    const int b  = blockIdx.x >> 9;
    const int tid = threadIdx.x;
    const int d  = gd * 256 + tid;
    const int t0 = c * LC;
    f32x2 A2[8];
    #pragma unroll
    for (int q = 0; q < 4; ++q) {
        float4 v = *(const float4*)&A_log[d * DSTATE + q * 4];
        A2[2*q]   = (f32x2){-__expf(v.x) * LOG2E, -__expf(v.y) * LOG2E};
        A2[2*q+1] = (f32x2){-__expf(v.z) * LOG2E, -__expf(v.w) * LOG2E};
    }
    f32x2 Wv[8];
    #pragma unroll
    for (int q = 0; q < 4; ++q) {
        float4 v = *(const float4*)&Wdt[d * DTR + q * 4];
        Wv[2*q]   = (f32x2){v.x, v.y};
        Wv[2*q+1] = (f32x2){v.z, v.w};
    }
    const float bd = bdt[d];
    {
        const __half* ub = u + ((long)b * L + t0) * DIN + gd * 256;
        #pragma unroll
        for (int j = 0; j < 2; ++j) {
            int i = tid + j * 256;            // 512 float4s = 16 rows x 32
            int t = i >> 5, col = (i & 31) * 8;
            *(float4*)&sU[t][col] = *(const float4*)&ub[(long)t * DIN + col];
        }
        if (tid < 64) {
            const float* Bb = Bm  + ((long)b * L + t0) * DSTATE;
            const float* Db = dtA + ((long)b * L + t0) * DTR;
            *(float4*)&((float*)sB)[tid * 4]  = *(const float4*)&Bb[tid * 4];
            *(float4*)&((float*)sDt)[tid * 4] = *(const float4*)&Db[tid * 4];
        }
    }
    __syncthreads();
    f32x2 X2[8];
    #pragma unroll
    for (int k = 0; k < 8; ++k) X2[k] = (f32x2){0.f, 0.f};
    float dsum = 0.f;
    const long gbase = ((long)b * L + t0) * DIN + d;
    #pragma unroll 2
    for (int t = 0; t < LC; ++t) {
        float qd[16], br[16];
        *(float4*)&qd[0]  = *(const float4*)&sDt[t][0];
        *(float4*)&qd[4]  = *(const float4*)&sDt[t][4];
        *(float4*)&qd[8]  = *(const float4*)&sDt[t][8];
        *(float4*)&qd[12] = *(const float4*)&sDt[t][12];
        f32x2 dpA = (f32x2){0.f, 0.f}, dpB = (f32x2){0.f, 0.f};
        #pragma unroll
        for (int k = 0; k < 8; k += 2) {
            dpA = fma2(*(const f32x2*)&qd[2*k],     Wv[k],     dpA);
            dpB = fma2(*(const f32x2*)&qd[2*k+2],   Wv[k+1],   dpB);
        }
        float dlt = softplus_fast(((dpA.x + dpA.y) + (dpB.x + dpB.y)) + bd);
        Dl[gbase + (long)t * DIN] = dlt;          // fp32 handoff to phase3
        dsum += dlt;
        float du = dlt * __half2float(sU[t][tid]);
        f32x2 du2  = (f32x2){du, du};
        f32x2 dlt2 = (f32x2){dlt, dlt};
        *(float4*)&br[0]  = *(const float4*)&sB[t][0];
        *(float4*)&br[4]  = *(const float4*)&sB[t][4];
        *(float4*)&br[8]  = *(const float4*)&sB[t][8];
        *(float4*)&br[12] = *(const float4*)&sB[t][12];
        #pragma unroll
        for (int k = 0; k < 8; ++k) {
            f32x2 tt = dlt2 * A2[k];
            f32x2 a2;
            a2.x = EXP2(tt.x);
            a2.y = EXP2(tt.y);
            X2[k] = fma2(a2, X2[k], du2 * *(const f32x2*)&br[2*k]);
        }
    }
    long o = (((long)b * NC + c) * DIN + d) * DSTATE;
    #pragma unroll
    for (int q = 0; q < 4; ++q)
        *(float4*)&Xc[o + q * 4] =
            make_float4(X2[2*q].x, X2[2*q].y, X2[2*q+1].x, X2[2*q+1].y);
    DS[((long)b * NC + c) * DIN + d] = dsum;
}

// cross-chunk scan: 32768 independent series; pure-ILP kernel.
// 8-chunk groups, depth-2 prefetch (16 loads/type in flight).
__global__ __launch_bounds__(256)
void scan_phase2(const float* __restrict__ Xc, const float* __restrict__ DS,
                 const float* __restrict__ A_log, float* __restrict__ Hout)
{
    int lane = blockIdx.x * 256 + threadIdx.x;   // 32768 total
    int b = lane >> 13;
    int rem = lane & 8191;                       // d*16 + s
    int d = rem >> 4;
    const float Ar = -__expf(A_log[rem]) * LOG2E;
    const long cs = (long)DIN * DSTATE;
    const long xb = (long)b * NC * cs + rem;
    const long db = (long)b * NC * DIN + d;
    float h = 0.f;
    float xc_[8], ts_[8], nx_[8], nt_[8];
    auto ldx = [&](int c) { return Xc[xb + (long)c * cs]; };
    auto ldt = [&](int c) { return DS[db + (long)c * DIN]; };
    #pragma unroll
    for (int j = 0; j < 8; ++j) { xc_[j] = ldx(j);     ts_[j] = ldt(j); }
    #pragma unroll
    for (int j = 0; j < 8; ++j) { nx_[j] = ldx(8 + j); nt_[j] = ldt(8 + j); }
    for (int c = 0; c < NC; c += 8) {
        #pragma unroll
        for (int j = 0; j < 8; ++j) {
            Hout[xb + (long)(c + j) * cs] = h;
            h = fmaf(EXP2(ts_[j] * Ar), h, xc_[j]);
        }
        #pragma unroll
        for (int j = 0; j < 8; ++j) { xc_[j] = nx_[j]; ts_[j] = nt_[j]; }
        if (c + 16 < NC) {
            #pragma unroll
            for (int j = 0; j < 8; ++j) {
                nx_[j] = ldx(c + 16 + j);
                nt_[j] = ldt(c + 16 + j);
            }
        }
    }
}

__global__ __launch_bounds__(256)
void scan_phase3(const float* __restrict__ Dl, const __half* __restrict__ u,
                 const float* __restrict__ Bm, const float* __restrict__ Cm,
                 const __half* __restrict__ z, const float* __restrict__ A_log,
                 const float* __restrict__ Dp, const float* __restrict__ Hinit,
                 __half* __restrict__ y2h)
{
    __shared__ float sB[LC][DSTATE], sC[LC][DSTATE];
    __shared__ float sDl[LC][256];
    __shared__ __half sU[LC][256];
    __shared__ __half sZ[LC][256];
    const int gd = blockIdx.x & 1;
    const int c  = (blockIdx.x >> 1) & (NC - 1);
    const int b  = blockIdx.x >> 9;
    const int tid = threadIdx.x;
    const int d  = gd * 256 + tid;
    const int t0 = c * LC;
    f32x2 A2[8];
    #pragma unroll
    for (int q = 0; q < 4; ++q) {
        float4 v = *(const float4*)&A_log[d * DSTATE + q * 4];
        A2[2*q]   = (f32x2){-__expf(v.x) * LOG2E, -__expf(v.y) * LOG2E};
        A2[2*q+1] = (f32x2){-__expf(v.z) * LOG2E, -__expf(v.w) * LOG2E};
    }
    {
        const __half* ub = u  + ((long)b * L + t0) * DIN + gd * 256;
        const __half* zb = z  + ((long)b * L + t0) * DIN + gd * 256;
        const float*  db = Dl + ((long)b * L + t0) * DIN + gd * 256;
        #pragma unroll
        for (int j = 0; j < 2; ++j) {
            int i = tid + j * 256;
            int t = i >> 5, col = (i & 31) * 8;
            *(float4*)&sU[t][col] = *(const float4*)&ub[(long)t * DIN + col];
            *(float4*)&sZ[t][col] = *(const float4*)&zb[(long)t * DIN + col];
        }
        #pragma unroll
        for (int j = 0; j < 4; ++j) {       // 1024 float4s for sDl
            int i = tid + j * 256;
            int t = i >> 6, col = (i & 63) * 4;
            *(float4*)&sDl[t][col] = *(const float4*)&db[(long)t * DIN + col];
        }
        if (tid < 64) {
            const float* Bb = Bm  + ((long)b * L + t0) * DSTATE;
            const float* Cb = Cm  + ((long)b * L + t0) * DSTATE;
            *(float4*)&((float*)sB)[tid * 4]  = *(const float4*)&Bb[tid * 4];
            *(float4*)&((float*)sC)[tid * 4]  = *(const float4*)&Cb[tid * 4];
        }
    }
    f32x2 h2[8];
    {
        long o = (((long)b * NC + c) * DIN + d) * DSTATE;
        #pragma unroll
        for (int q = 0; q < 4; ++q) {
            float4 v = *(const float4*)&Hinit[o + q * 4];
            h2[2*q]   = (f32x2){v.x, v.y};
            h2[2*q+1] = (f32x2){v.z, v.w};
        }
    }
    const float Dval = Dp[d];
    const long gbase = ((long)b * L + t0) * DIN + d;
    __syncthreads();
    #pragma unroll 2
    for (int t = 0; t < LC; ++t) {
        float br[16], cr[16];
        float dlt = sDl[t][tid];                  // replaces dp-dot + softplus
        float uu = __half2float(sU[t][tid]);
        float zz = __half2float(sZ[t][tid]);
        float du = dlt * uu;
        f32x2 du2  = (f32x2){du, du};
        f32x2 dlt2 = (f32x2){dlt, dlt};
        *(float4*)&br[0]  = *(const float4*)&sB[t][0];
        *(float4*)&br[4]  = *(const float4*)&sB[t][4];
        *(float4*)&br[8]  = *(const float4*)&sB[t][8];
        *(float4*)&br[12] = *(const float4*)&sB[t][12];
        *(float4*)&cr[0]  = *(const float4*)&sC[t][0];
        *(float4*)&cr[4]  = *(const float4*)&sC[t][4];
        *(float4*)&cr[8]  = *(const float4*)&sC[t][8];
        *(float4*)&cr[12] = *(const float4*)&sC[t][12];
        f32x2 y2a = (f32x2){0.f, 0.f}, y2b = (f32x2){0.f, 0.f};
        f32x2 y2c = (f32x2){0.f, 0.f}, y2d = (f32x2){0.f, 0.f};
        #pragma unroll
        for (int k = 0; k < 8; k += 4) {
            f32x2 t0v = dlt2 * A2[k+0];
            f32x2 t1v = dlt2 * A2[k+1];
            f32x2 t2v = dlt2 * A2[k+2];
            f32x2 t3v = dlt2 * A2[k+3];
            f32x2 a0, a1, a2v, a3;
            a0.x = EXP2(t0v.x); a0.y = EXP2(t0v.y);
            a1.x = EXP2(t1v.x); a1.y = EXP2(t1v.y);
            a2v.x = EXP2(t2v.x); a2v.y = EXP2(t2v.y);
            a3.x = EXP2(t3v.x); a3.y = EXP2(t3v.y);
            h2[k+0] = fma2(h2[k+0], a0,  du2 * *(const f32x2*)&br[2*k+0]);
            h2[k+1] = fma2(h2[k+1], a1,  du2 * *(const f32x2*)&br[2*k+2]);
            h2[k+2] = fma2(h2[k+2], a2v, du2 * *(const f32x2*)&br[2*k+4]);
            h2[k+3] = fma2(h2[k+3], a3,  du2 * *(const f32x2*)&br[2*k+6]);
            y2a = fma2(h2[k+0], *(const f32x2*)&cr[2*k+0], y2a);
            y2b = fma2(h2[k+1], *(const f32x2*)&cr[2*k+2], y2b);
            y2c = fma2(h2[k+2], *(const f32x2*)&cr[2*k+4], y2c);
            y2d = fma2(h2[k+3], *(const f32x2*)&cr[2*k+6], y2d);
        }
        f32x2 ys = (y2a + y2b) + (y2c + y2d);
        float y = ys.x + ys.y;
        y2h[gbase + t * DIN] = __float2half((y + uu * Dval) * silu_f(zz));
    }
}

// ---------------- LayerNorm over C + transpose to (B,C,L) ----------------
__global__ __launch_bounds__(256)
void ln_kernel(const float* __restrict__ X, const float* __restrict__ gamma,
               const float* __restrict__ beta, float* __restrict__ out)
{
    __shared__ float tile[32][257];
    __shared__ float sMu[32], sRs[32];
    const int l0 = blockIdx.x * 32;
    const int b  = blockIdx.y;
    const int tid = threadIdx.x;
    for (int i = tid; i < 32 * 256; i += 256) {
        int l = i >> 8, c = i & 255;
        tile[l][c] = X[((long)b * L + l0 + l) * CDIM + c];
    }
    __syncthreads();
    {
        int l = tid >> 3, sub = tid & 7;
        float s1 = 0.f, s2 = 0.f;
        for (int c = sub * 32; c < sub * 32 + 32; ++c) {
            float v = tile[l][c];
            s1 += v; s2 += v * v;
        }
        s1 += __shfl_xor(s1, 1); s2 += __shfl_xor(s2, 1);
        s1 += __shfl_xor(s1, 2); s2 += __shfl_xor(s2, 2);
        s1 += __shfl_xor(s1, 4); s2 += __shfl_xor(s2, 4);
        if (sub == 0) {
            float mu = s1 * (1.f / 256.f);
            float var = s2 * (1.f / 256.f) - mu * mu;
            sMu[l] = mu;
            sRs[l] = rsqrtf(var + 1e-5f);
        }
    }
    __syncthreads();
    for (int i = tid; i < 32 * 256; i += 256) {
        int ll = i & 31, c = i >> 5;
        float v = (tile[ll][c] - sMu[ll]) * sRs[ll] * gamma[c] + beta[c];
        out[((long)b * CDIM + c) * L + l0 + ll] = v;
    }
}

extern "C" void kernel_launch(void* const* d_in, const int* in_sizes, int n_in,
                              void* d_out, int out_size, void* d_ws, size_t ws_size,
                              hipStream_t stream)
{
    const float* sp   = (const float*)d_in[0];
    const float* fq   = (const float*)d_in[1];
    const float* Wp   = (const float*)d_in[2];
    const float* bp   = (const float*)d_in[3];
    const float* Win  = (const float*)d_in[4];
    const float* cw   = (const float*)d_in[5];
    const float* cb   = (const float*)d_in[6];
    const float* Wx   = (const float*)d_in[7];
    const float* Wdt  = (const float*)d_in[8];
    const float* bdt  = (const float*)d_in[9];
    const float* Alog = (const float*)d_in[10];
    const float* Dp   = (const float*)d_in[11];
    const float* Wout = (const float*)d_in[12];
    const float* gam  = (const float*)d_in[13];
    const float* bet  = (const float*)d_in[14];
    float* out = (float*)d_out;
    float* ws  = (float*)d_ws;

    const size_t NLD = (size_t)BATCH * L * DIN;   // 8.39M
    const size_t NLC = (size_t)BATCH * L * CDIM;  // 4.19M

    size_t off = 0;
    __half* u16   = (__half*)(ws + off); off += NLD / 2;  // pre-conv u
    __half* u16c  = (__half*)(ws + off); off += NLD / 2;  // post-conv silu(u)
    __half* z16   = (__half*)(ws + off); off += NLD / 2;
    __half* y16   = (__half*)(ws + off); off += NLD / 2;
    __half* xp16  = (__half*)(ws + off); off += NLC / 2;
    float*  xmix  = ws + off; off += NLC;
    float*  dtA   = ws + off; off += (size_t)BATCH * L * DTR;
    float*  Dl    = ws + off; off += NLD;                 // fp32 delta handoff
    __half* wph   = (__half*)(ws + off); off += SZ_WP / 2;
    __half* winh  = (__half*)(ws + off); off += SZ_WIN / 2;
    __half* woh   = (__half*)(ws + off); off += SZ_WO / 2;
    __half* wch   = (__half*)(ws + off); off += SZ_WC / 2;
    float*  Bmb   = ws + off; off += (size_t)BATCH * L * DSTATE;
    float*  Cmb   = ws + off; off += (size_t)BATCH * L * DSTATE;
    float*  Xc    = ws + off; off += (size_t)BATCH * NC * DIN * DSTATE;
    float*  DS    = ws + off; off += (size_t)BATCH * NC * DIN;
    float*  Hout  = ws + off; off += (size_t)BATCH * NC * DIN * DSTATE;

    dim3 blk(256);
    pack_all<<<dim3((SZ_WP + SZ_WIN + SZ_WO + SZ_WC) / 256), blk, 0, stream>>>(
        Wp, Win, Wout, Wx, wph, winh, woh, wch);

    // GEMM1: x_proj = x_cat @ Wp^T + bp  (A fp32 K-major reg-staged; B gload_lds)
    hgemm_g<HEPI_XP, true, 2><<<dim3(BATCH * (L/64) * 4), blk, 0, stream>>>(
        sp, fq, nullptr, wph, bp, nullptr, xp16, nullptr,
        L, CDIM, 2 * CDIM, CDIM, (long)CDIM * L, 4);
    // GEMM2: xz = x_proj @ Win^T -> u16 / z16  (full gload_lds staging)
    hgemm_g<HEPI_UZ, false, 4><<<dim3(BATCH * (L/64) * 8), blk, 0, stream>>>(
        nullptr, nullptr, xp16, winh, nullptr, nullptr, u16, z16,
        L, 2 * DIN, CDIM, 1 << 30, (long)L * CDIM, 8);

    conv_silu_kernel<<<dim3((int)(NLD / 8 / 256)), blk, 0, stream>>>(u16, cw, cb, u16c);
    // D34 rank-16: dbc = u @ Wx^T (N=48: dt|Bm|Cm) -- old kernel (OOB guard)
    hgemm<HEPI_D34, 2><<<dim3(BATCH * (L/64) * 1), blk, 0, stream>>>(
        u16c, wch, dtA, Bmb, Cmb, L, 48, DIN, (long)L * DIN, 1);

    scan_phase1<<<dim3(BATCH * NC * 2), blk, 0, stream>>>(
        dtA, u16c, Bmb, Alog, Wdt, bdt, Xc, DS, Dl);
    scan_phase2<<<dim3(BATCH * DIN * DSTATE / 256), blk, 0, stream>>>(Xc, DS, Alog, Hout);
    scan_phase3<<<dim3(BATCH * NC * 2), blk, 0, stream>>>(
        Dl, u16c, Bmb, Cmb, z16, Alog, Dp, Hout, y16);

    // GEMM5: x_mixed = y2 @ Wout^T  (full gload_lds staging)
    hgemm_g<HEPI_F32, false, 2><<<dim3(BATCH * (L/64) * 4), blk, 0, stream>>>(
        nullptr, nullptr, y16, woh, nullptr, xmix, nullptr, nullptr,
        L, CDIM, DIN, 1 << 30, (long)L * DIN, 4);
    ln_kernel<<<dim3(L / 32, BATCH), blk, 0, stream>>>(xmix, gam, bet, out);
}

// Round 13
// 297.542 us; speedup vs baseline: 1.0315x; 1.0006x over previous
//
#include <hip/hip_runtime.h>
#include <hip/hip_fp16.h>
#include <math.h>

#define L 4096
#define CDIM 256
#define DIN 512
#define DSTATE 16
#define DTR 16
#define BATCH 4

using f32x4  = __attribute__((ext_vector_type(4))) float;
using f32x2  = __attribute__((ext_vector_type(2))) float;
using f16x8  = __attribute__((ext_vector_type(8))) _Float16;

#define LOG2E 1.44269504088896f

#if __has_builtin(__builtin_amdgcn_exp2f)
#define EXP2(x) __builtin_amdgcn_exp2f(x)
#else
#define EXP2(x) __expf((x) * 0.69314718056f)
#endif

__device__ __forceinline__ float silu_f(float x) {
    return __fdividef(x, 1.f + __expf(-x));
}
__device__ __forceinline__ float softplus_fast(float x) {
    return (x > 20.f) ? x : __logf(1.f + __expf(x));
}
__device__ __forceinline__ unsigned pk2h(float a, float b) {
    __half2 h = __floats2half2_rn(a, b);
    return *reinterpret_cast<unsigned*>(&h);
}

// async global->LDS, 16B per lane, dest = wave-uniform base + lane*16
__device__ __forceinline__ void gload_lds16(const void* g, void* l) {
    __builtin_amdgcn_global_load_lds(
        (const __attribute__((address_space(1))) void*)g,
        (__attribute__((address_space(3))) void*)l, 16, 0, 0);
}

// LESSONS (measured, do not repeat):
//  - r1: lgkm-only barrier + depth-2 reg prefetch regressed GEMMs.
//  - r4: trans->VALU conversion regressed scans; delete VALU, keep trans.
//  - r5: 128x128 tile regressed GEMMs (occupancy hides stalls; 64-tile wins).
//  - r6: pk-f32 scan math WORKED (-15%).
//  - r8: gload_lds + LDK32 swizzle WORKED: GEMMs left top-5. 300.6us.
//  - r9: conv vectorization + traffic cut: 297.7us.
//  - r10: occupancy x2 -> phase3 +4% only. NOT wave-starved.
//  - r11: deleting 12/14 LDS reads -> phase3 UNCHANGED. NOT LDS-pipe-bound.
//  - r12: delta handoff neutral (VALU saved = Dl traffic paid). 297.7us.
//  - r13 theory: cycle accounting fails to close by ~5x; VGPR=40-48 is too low
//    for the live state; type-punned local float arrays (float4-write/f32x2-read)
//    likely defeated SROA -> scratch. Refactor scans to pure named-SSA f32x2.
//  - WRITE_SIZE on early dispatches includes harness memset traffic (artifact).

enum { HEPI_XP = 0, HEPI_UZ = 1, HEPI_F32 = 2, HEPI_D34 = 3 };

// ====== hgemm_g: 64-row tiles, global_load_lds staging, LDK=32 + XOR swizzle ======
template<int EPI, bool A_F32KM, int NT>
__global__ __launch_bounds__(256)
void hgemm_g(const float* __restrict__ Af0, const float* __restrict__ Af1,
             const __half* __restrict__ Ah_g, const __half* __restrict__ Bh_g,
             const float* __restrict__ bias,
             float* __restrict__ O0, __half* __restrict__ Oh0, __half* __restrict__ Oh1,
             int M, int N, int K, int kSplit, long strideAb, int nBlk)
{
    constexpr int BM = 64, MT = 2;
    constexpr int BN = 2 * NT * 16;         // 64 or 128
    constexpr int BCH = BN / 64;            // B gload instrs per wave: 1 or 2
    __shared__ __align__(16) _Float16 Ah[2][BM][32];
    __shared__ __align__(16) _Float16 Bh[2][BN][32];
    const int mBlk = M / BM;
    // XCD-sticky swizzle
    const int bid = blockIdx.x;
    const int r = bid & 7, q = bid >> 3;
    const int ni = q % nBlk;
    const int mg = (q / nBlk) * 8 + r;
    const int b = mg / mBlk, m_idx = mg - b * mBlk;
    const int n0 = ni * BN, m0 = m_idx * BM;
    const int tid  = threadIdx.x;
    const int lane = tid & 63;
    const int w    = tid >> 6;
    const int wr   = w >> 1, wc = w & 1;
    const int lrow = lane & 15;
    const int loct = lane >> 4;
    // gload source mapping: lane l -> row-in-chunk l>>2, swizzled k-octet kc
    const int gsub = lane >> 2;
    const int kc   = (lane & 3) ^ ((lane >> 3) & 3);
    // read-side swizzled column (f16 units), lane-constant
    const int swc  = (loct ^ ((lrow >> 1) & 3)) * 8;

    f32x4 acc[MT][NT];
    #pragma unroll
    for (int i = 0; i < MT; ++i)
        #pragma unroll
        for (int j = 0; j < NT; ++j)
            acc[i][j] = (f32x4){0.f, 0.f, 0.f, 0.f};

    float va[8];
    auto loadA32 = [&](int kk) {        // GEMM1: fp32 K-major A -> regs (needs cvt)
        if constexpr (A_F32KM) {
            int m = tid & 63, ks = tid >> 6;
            #pragma unroll
            for (int j = 0; j < 8; ++j) {
                int kg = kk + ks * 8 + j;
                const float* Ap; int kl;
                if (kg < kSplit) { Ap = Af0; kl = kg; } else { Ap = Af1; kl = kg - kSplit; }
                va[j] = Ap[(long)b * strideAb + (long)kl * M + m0 + m];
            }
        }
    };
    auto storeA32 = [&](int buf) {      // swizzled ds_write (matches read XOR)
        if constexpr (A_F32KM) {
            int m = tid & 63, ks = tid >> 6;
            int ksw = (ks ^ ((m >> 1) & 3)) * 8;
            uint4 h;
            h.x = pk2h(va[0], va[1]);
            h.y = pk2h(va[2], va[3]);
            h.z = pk2h(va[4], va[5]);
            h.w = pk2h(va[6], va[7]);
            *(uint4*)&Ah[buf][m][ksw] = h;
        }
    };
    auto stageA = [&](int kk, int buf) {
        if constexpr (!A_F32KM) {
            const __half* src = Ah_g + (long)b * strideAb +
                                (long)(m0 + w * 16 + gsub) * K + kk + kc * 8;
            gload_lds16(src, &Ah[buf][w * 16][0]);
        }
    };
    auto stageB = [&](int kk, int buf) {
        #pragma unroll
        for (int p = 0; p < BCH; ++p) {
            int ch = w * BCH + p;       // 16-row chunk index
            const __half* src = Bh_g + (long)(n0 + ch * 16 + gsub) * K + kk + kc * 8;
            gload_lds16(src, &Bh[buf][ch * 16][0]);
        }
    };

    loadA32(0);
    stageA(0, 0); stageB(0, 0);
    storeA32(0);
    __syncthreads();                    // drains vmcnt -> gloads landed
    int cur = 0;
    for (int kk = 0; kk < K; kk += 32) {
        const bool more = (kk + 32 < K);
        if (more) {
            loadA32(kk + 32);
            stageA(kk + 32, cur ^ 1);   // async, direct to LDS buf^1
            stageB(kk + 32, cur ^ 1);
        }
        f16x8 bh[NT];
        #pragma unroll
        for (int nt = 0; nt < NT; ++nt)
            bh[nt] = *(const f16x8*)&Bh[cur][wc*NT*16 + nt*16 + lrow][swc];
        #pragma unroll
        for (int mt = 0; mt < MT; ++mt) {
            f16x8 ah = *(const f16x8*)&Ah[cur][wr*MT*16 + mt*16 + lrow][swc];
            #pragma unroll
            for (int nt = 0; nt < NT; ++nt)
                acc[mt][nt] = __builtin_amdgcn_mfma_f32_16x16x32_f16(ah, bh[nt], acc[mt][nt], 0, 0, 0);
        }
        if (more) {
            storeA32(cur ^ 1);
            __syncthreads();            // ONE barrier per k-iter (r0 schedule)
            cur ^= 1;
        }
    }
    // epilogue: C/D col=lane&15, row=(lane>>4)*4+reg
    #pragma unroll
    for (int mt = 0; mt < MT; ++mt) {
        #pragma unroll
        for (int r4 = 0; r4 < 4; ++r4) {
            int m = m0 + wr*MT*16 + mt * 16 + loct * 4 + r4;
            long rowb = (long)b * M + m;
            #pragma unroll
            for (int nt = 0; nt < NT; ++nt) {
                int n = n0 + wc*NT*16 + nt * 16 + lrow;
                float v = acc[mt][nt][r4];
                if constexpr (EPI == HEPI_XP) {
                    Oh0[rowb * N + n] = __float2half(v + bias[n]);
                } else if constexpr (EPI == HEPI_UZ) {
                    if (n < DIN) Oh0[rowb * DIN + n] = __float2half(v);
                    else         Oh1[rowb * DIN + (n - DIN)] = __float2half(v);
                } else {
                    O0[rowb * N + n] = v;
                }
            }
        }
    }
}

#define LDK 40
// ====== old reg-staged hgemm (LDK=40): kept ONLY for D34 (needs OOB zero-guard) ===
template<int EPI, int NT>
__global__ __launch_bounds__(256)
void hgemm(const __half* __restrict__ Ah_g, const __half* __restrict__ Bh_g,
           float* __restrict__ O0, float* __restrict__ Ob, float* __restrict__ Oc,
           int M, int N, int K, long strideAb, int nBlk)
{
    constexpr int BM = 64, MT = 2;
    constexpr int BN = 2 * NT * 16;
    constexpr int BSEG = BN / 64;
    __shared__ __align__(16) _Float16 Ah[2][BM][LDK];
    __shared__ __align__(16) _Float16 Bh[2][BN][LDK];
    const int mBlk = M / BM;
    const int bid = blockIdx.x;
    const int r = bid & 7, q = bid >> 3;
    const int ni = q % nBlk;
    const int mg = (q / nBlk) * 8 + r;
    const int b = mg / mBlk, m_idx = mg - b * mBlk;
    const int n0 = ni * BN, m0 = m_idx * BM;
    const int tid  = threadIdx.x;
    const int lane = tid & 63;
    const int w    = tid >> 6;
    const int wr   = w >> 1, wc = w & 1;
    const int lrow = lane & 15;
    const int loct = lane >> 4;

    f32x4 acc[MT][NT];
    #pragma unroll
    for (int i = 0; i < MT; ++i)
        #pragma unroll
        for (int j = 0; j < NT; ++j)
            acc[i][j] = (f32x4){0.f, 0.f, 0.f, 0.f};

    const int sOct = tid & 3, sRow = tid >> 2;
    uint4 pa, pb[BSEG];

    auto loadA = [&](int kk) {
        pa = *(const uint4*)(Ah_g + (long)b * strideAb +
                             (long)(m0 + sRow) * K + kk + sOct * 8);
    };
    auto loadB = [&](int kk) {
        #pragma unroll
        for (int p = 0; p < BSEG; ++p) {
            int ng = n0 + sRow + p * 64;
            if (ng >= N) pb[p] = make_uint4(0, 0, 0, 0);
            else pb[p] = *(const uint4*)(Bh_g + (long)ng * K + kk + sOct * 8);
        }
    };
    auto storeAB = [&](int buf) {
        *(uint4*)&Ah[buf][sRow][sOct * 8] = pa;
        #pragma unroll
        for (int p = 0; p < BSEG; ++p)
            *(uint4*)&Bh[buf][sRow + p * 64][sOct * 8] = pb[p];
    };

    loadA(0); loadB(0);
    storeAB(0);
    __syncthreads();
    int cur = 0;
    for (int kk = 0; kk < K; kk += 32) {
        const bool more = (kk + 32 < K);
        if (more) { loadA(kk + 32); loadB(kk + 32); }
        f16x8 bh[NT];
        #pragma unroll
        for (int nt = 0; nt < NT; ++nt)
            bh[nt] = *(const f16x8*)&Bh[cur][wc*NT*16 + nt*16 + lrow][loct*8];
        #pragma unroll
        for (int mt = 0; mt < MT; ++mt) {
            f16x8 ah = *(const f16x8*)&Ah[cur][wr*MT*16 + mt*16 + lrow][loct*8];
            #pragma unroll
            for (int nt = 0; nt < NT; ++nt)
                acc[mt][nt] = __builtin_amdgcn_mfma_f32_16x16x32_f16(ah, bh[nt], acc[mt][nt], 0, 0, 0);
        }
        if (more) {
            storeAB(cur ^ 1);
            __syncthreads();
            cur ^= 1;
        }
    }
    #pragma unroll
    for (int mt = 0; mt < MT; ++mt) {
        #pragma unroll
        for (int r4 = 0; r4 < 4; ++r4) {
            int m = m0 + wr*MT*16 + mt * 16 + loct * 4 + r4;
            long rowb = (long)b * M + m;
            #pragma unroll
            for (int nt = 0; nt < NT; ++nt) {
                int n = n0 + wc*NT*16 + nt * 16 + lrow;
                float v = acc[mt][nt][r4];
                if (n < DTR)           O0[rowb * DTR + n] = v;
                else if (n < 2 * DTR)  Ob[rowb * 16 + (n - DTR)] = v;
                else if (n < 48)       Oc[rowb * 16 + (n - 32)] = v;
            }
        }
    }
}

// ---------------- weight prep: fp16 casts ---------
#define SZ_WP  131072
#define SZ_WIN 262144
#define SZ_WO  131072
#define SZ_WC  24576
__global__ __launch_bounds__(256)
void pack_all(const float* __restrict__ Wp, const float* __restrict__ Win,
              const float* __restrict__ Wout, const float* __restrict__ Wx,
              __half* __restrict__ wph, __half* __restrict__ winh,
              __half* __restrict__ woh, __half* __restrict__ wch)
{
    int i = blockIdx.x * 256 + threadIdx.x;
    if (i < SZ_WP) { wph[i] = __float2half(Wp[i]); return; }
    i -= SZ_WP;
    if (i < SZ_WIN) { winh[i] = __float2half(Win[i]); return; }
    i -= SZ_WIN;
    if (i < SZ_WO) { woh[i] = __float2half(Wout[i]); return; }
    i -= SZ_WO;
    if (i < SZ_WC) wch[i] = __float2half(Wx[i]);   // (48, 512) row-major
}

// ------- depthwise causal conv (k=4) + silu: VECTORIZED 8 d's/thread (G13) -------
__global__ __launch_bounds__(256)
void conv_silu_kernel(const __half* __restrict__ u_pre, const float* __restrict__ cw,
                      const float* __restrict__ cb, __half* __restrict__ u)
{
    long gid = (long)blockIdx.x * 256 + threadIdx.x;   // NLD/8 threads
    const int dv = (int)(gid & 63);                    // d0 = dv*8
    const long bl = gid >> 6;                          // b*L + l
    const int l = (int)(bl & (L - 1));
    const long brow = bl - l;
    const int d0 = dv * 8;

    float acc[8];
    {
        float4 c0 = *(const float4*)&cb[d0];
        float4 c1 = *(const float4*)&cb[d0 + 4];
        acc[0]=c0.x; acc[1]=c0.y; acc[2]=c0.z; acc[3]=c0.w;
        acc[4]=c1.x; acc[5]=c1.y; acc[6]=c1.z; acc[7]=c1.w;
    }
    float4 wrow[8];                                    // cw rows (hot 8KB in L2)
    #pragma unroll
    for (int e = 0; e < 8; ++e) wrow[e] = *(const float4*)&cw[(d0 + e) * 4];

    #pragma unroll
    for (int j = 0; j < 4; ++j) {
        int li = l - 3 + j;                            // wave-uniform branch
        if (li >= 0) {
            uint4 raw = *(const uint4*)(u_pre + (brow + li) * DIN + d0);
            const __half2* h2 = (const __half2*)&raw;
            #pragma unroll
            for (int e = 0; e < 4; ++e) {
                float2 f = __half22float2(h2[e]);
                float w0 = (j == 0) ? wrow[2*e].x : (j == 1) ? wrow[2*e].y
                         : (j == 2) ? wrow[2*e].z : wrow[2*e].w;
                float w1 = (j == 0) ? wrow[2*e+1].x : (j == 1) ? wrow[2*e+1].y
                         : (j == 2) ? wrow[2*e+1].z : wrow[2*e+1].w;
                acc[2*e]   = fmaf(f.x, w0, acc[2*e]);
                acc[2*e+1] = fmaf(f.y, w1, acc[2*e+1]);
            }
        }
    }
    uint4 st;
    st.x = pk2h(silu_f(acc[0]), silu_f(acc[1]));
    st.y = pk2h(silu_f(acc[2]), silu_f(acc[3]));
    st.z = pk2h(silu_f(acc[4]), silu_f(acc[5]));
    st.w = pk2h(silu_f(acc[6]), silu_f(acc[7]));
    *(uint4*)(u + bl * DIN + d0) = st;
}

// ---------------- chunked parallel selective scan, d-per-lane ----------------
// r13: pure named-SSA f32x2 inner loops -- no local float arrays, no
// float4-write/f32x2-read type-pun round-trips (rule #20 / SROA hazard).
#define NC 256
#define LC (L / NC)

__device__ __forceinline__ f32x2 fma2(f32x2 a, f32x2 b, f32x2 c) {
    return __builtin_elementwise_fma(a, b, c);
}
__device__ __forceinline__ void ld4s(const float* p, f32x2& lo, f32x2& hi) {
    f32x4 v = *(const f32x4*)p;
    lo = __builtin_shufflevector(v, v, 0, 1);
    hi = __builtin_shufflevector(v, v, 2, 3);
}

#define LDA2(qi, lo, hi) { \
    float4 v_ = *(const float4*)&A_log[d * DSTATE + (qi) * 4]; \
    lo = (f32x2){-__expf(v_.x) * LOG2E, -__expf(v_.y) * LOG2E}; \
    hi = (f32x2){-__expf(v_.z) * LOG2E, -__expf(v_.w) * LOG2E}; }

#define LDW2(qi, lo, hi) { \
    float4 v_ = *(const float4*)&Wdt[d * DTR + (qi) * 4]; \
    lo = (f32x2){v_.x, v_.y}; hi = (f32x2){v_.z, v_.w}; }

__global__ __launch_bounds__(256)
void scan_phase1(const float* __restrict__ dtA, const __half* __restrict__ u,
                 const float* __restrict__ Bm, const float* __restrict__ A_log,
                 const float* __restrict__ Wdt, const float* __restrict__ bdt,
                 float* __restrict__ Xc, float* __restrict__ DS,
                 float* __restrict__ Dl)
{
    __shared__ float sB[LC][DSTATE];
    __shared__ float sDt[LC][DTR];
    __shared__ __half sU[LC][256];
    const int gd = blockIdx.x & 1;
    const int c  = (blockIdx.x >> 1) & (NC - 1);
    const int b  = blockIdx.x >> 9;
    const int tid = threadIdx.x;
    const int d  = gd * 256 + tid;
    const int t0 = c * LC;
    f32x2 A20, A21, A22, A23, A24, A25, A26, A27;
    LDA2(0, A20, A21) LDA2(1, A22, A23) LDA2(2, A24, A25) LDA2(3, A26, A27)
    f32x2 W0, W1, W2, W3, W4, W5, W6, W7;
    LDW2(0, W0, W1) LDW2(1, W2, W3) LDW2(2, W4, W5) LDW2(3, W6, W7)
    const float bd = bdt[d];
    {
        const __half* ub = u + ((long)b * L + t0) * DIN + gd * 256;
        #pragma unroll
        for (int j = 0; j < 2; ++j) {
            int i = tid + j * 256;            // 512 float4s = 16 rows x 32
            int t = i >> 5, col = (i & 31) * 8;
            *(float4*)&sU[t][col] = *(const float4*)&ub[(long)t * DIN + col];
        }
        if (tid < 64) {
            const float* Bb = Bm  + ((long)b * L + t0) * DSTATE;
            const float* Db = dtA + ((long)b * L + t0) * DTR;
            *(float4*)&((float*)sB)[tid * 4]  = *(const float4*)&Bb[tid * 4];
            *(float4*)&((float*)sDt)[tid * 4] = *(const float4*)&Db[tid * 4];
        }
    }
    __syncthreads();
    f32x2 X20 = {0,0}, X21 = {0,0}, X22 = {0,0}, X23 = {0,0};
    f32x2 X24 = {0,0}, X25 = {0,0}, X26 = {0,0}, X27 = {0,0};
    float dsum = 0.f;
    const long gbase = ((long)b * L + t0) * DIN + d;
    #pragma unroll 2
    for (int t = 0; t < LC; ++t) {
        f32x2 q0, q1, q2, q3, q4, q5, q6, q7;
        ld4s(&sDt[t][0],  q0, q1);
        ld4s(&sDt[t][4],  q2, q3);
        ld4s(&sDt[t][8],  q4, q5);
        ld4s(&sDt[t][12], q6, q7);
        f32x2 dpA = q0 * W0, dpB = q1 * W1;
        dpA = fma2(q2, W2, dpA); dpB = fma2(q3, W3, dpB);
        dpA = fma2(q4, W4, dpA); dpB = fma2(q5, W5, dpB);
        dpA = fma2(q6, W6, dpA); dpB = fma2(q7, W7, dpB);
        float dlt = softplus_fast(((dpA.x + dpA.y) + (dpB.x + dpB.y)) + bd);
        Dl[gbase + (long)t * DIN] = dlt;          // fp32 handoff to phase3
        dsum += dlt;
        float du = dlt * __half2float(sU[t][tid]);
        f32x2 du2  = (f32x2){du, du};
        f32x2 dlt2 = (f32x2){dlt, dlt};
        f32x2 b0, b1, b2, b3, b4, b5, b6, b7;
        ld4s(&sB[t][0],  b0, b1);
        ld4s(&sB[t][4],  b2, b3);
        ld4s(&sB[t][8],  b4, b5);
        ld4s(&sB[t][12], b6, b7);
#define P1K(k) { f32x2 tt = dlt2 * A2##k; f32x2 a_; \
        a_.x = EXP2(tt.x); a_.y = EXP2(tt.y); \
        X2##k = fma2(a_, X2##k, du2 * b##k); }
        P1K(0) P1K(1) P1K(2) P1K(3) P1K(4) P1K(5) P1K(6) P1K(7)
#undef P1K
    }
    long o = (((long)b * NC + c) * DIN + d) * DSTATE;
    *(float4*)&Xc[o + 0]  = make_float4(X20.x, X20.y, X21.x, X21.y);
    *(float4*)&Xc[o + 4]  = make_float4(X22.x, X22.y, X23.x, X23.y);
    *(float4*)&Xc[o + 8]  = make_float4(X24.x, X24.y, X25.x, X25.y);
    *(float4*)&Xc[o + 12] = make_float4(X26.x, X26.y, X27.x, X27.y);
    DS[((long)b * NC + c) * DIN + d] = dsum;
}

// cross-chunk scan: 32768 independent series; pure-ILP kernel.
__global__ __launch_bounds__(256)
void scan_phase2(const float* __restrict__ Xc, const float* __restrict__ DS,
                 const float* __restrict__ A_log, float* __restrict__ Hout)
{
    int lane = blockIdx.x * 256 + threadIdx.x;   // 32768 total
    int b = lane >> 13;
    int rem = lane & 8191;                       // d*16 + s
    int d = rem >> 4;
    const float Ar = -__expf(A_log[rem]) * LOG2E;
    const long cs = (long)DIN * DSTATE;
    const long xb = (long)b * NC * cs + rem;
    const long db = (long)b * NC * DIN + d;
    float h = 0.f;
    float xc_[8], ts_[8], nx_[8], nt_[8];
    auto ldx = [&](int c) { return Xc[xb + (long)c * cs]; };
    auto ldt = [&](int c) { return DS[db + (long)c * DIN]; };
    #pragma unroll
    for (int j = 0; j < 8; ++j) { xc_[j] = ldx(j);     ts_[j] = ldt(j); }
    #pragma unroll
    for (int j = 0; j < 8; ++j) { nx_[j] = ldx(8 + j); nt_[j] = ldt(8 + j); }
    for (int c = 0; c < NC; c += 8) {
        #pragma unroll
        for (int j = 0; j < 8; ++j) {
            Hout[xb + (long)(c + j) * cs] = h;
            h = fmaf(EXP2(ts_[j] * Ar), h, xc_[j]);
        }
        #pragma unroll
        for (int j = 0; j < 8; ++j) { xc_[j] = nx_[j]; ts_[j] = nt_[j]; }
        if (c + 16 < NC) {
            #pragma unroll
            for (int j = 0; j < 8; ++j) {
                nx_[j] = ldx(c + 16 + j);
                nt_[j] = ldt(c + 16 + j);
            }
        }
    }
}

__global__ __launch_bounds__(256)
void scan_phase3(const float* __restrict__ Dl, const __half* __restrict__ u,
                 const float* __restrict__ Bm, const float* __restrict__ Cm,
                 const __half* __restrict__ z, const float* __restrict__ A_log,
                 const float* __restrict__ Dp, const float* __restrict__ Hinit,
                 __half* __restrict__ y2h)
{
    __shared__ float sB[LC][DSTATE], sC[LC][DSTATE];
    __shared__ float sDl[LC][256];
    __shared__ __half sU[LC][256];
    __shared__ __half sZ[LC][256];
    const int gd = blockIdx.x & 1;
    const int c  = (blockIdx.x >> 1) & (NC - 1);
    const int b  = blockIdx.x >> 9;
    const int tid = threadIdx.x;
    const int d  = gd * 256 + tid;
    const int t0 = c * LC;
    f32x2 A20, A21, A22, A23, A24, A25, A26, A27;
    LDA2(0, A20, A21) LDA2(1, A22, A23) LDA2(2, A24, A25) LDA2(3, A26, A27)
    {
        const __half* ub = u  + ((long)b * L + t0) * DIN + gd * 256;
        const __half* zb = z  + ((long)b * L + t0) * DIN + gd * 256;
        const float*  db = Dl + ((long)b * L + t0) * DIN + gd * 256;
        #pragma unroll
        for (int j = 0; j < 2; ++j) {
            int i = tid + j * 256;
            int t = i >> 5, col = (i & 31) * 8;
            *(float4*)&sU[t][col] = *(const float4*)&ub[(long)t * DIN + col];
            *(float4*)&sZ[t][col] = *(const float4*)&zb[(long)t * DIN + col];
        }
        #pragma unroll
        for (int j = 0; j < 4; ++j) {       // 1024 float4s for sDl
            int i = tid + j * 256;
            int t = i >> 6, col = (i & 63) * 4;
            *(float4*)&sDl[t][col] = *(const float4*)&db[(long)t * DIN + col];
        }
        if (tid < 64) {
            const float* Bb = Bm  + ((long)b * L + t0) * DSTATE;
            const float* Cb = Cm  + ((long)b * L + t0) * DSTATE;
            *(float4*)&((float*)sB)[tid * 4]  = *(const float4*)&Bb[tid * 4];
            *(float4*)&((float*)sC)[tid * 4]  = *(const float4*)&Cb[tid * 4];
        }
    }
    f32x2 h20, h21, h22, h23, h24, h25, h26, h27;
    {
        long o = (((long)b * NC + c) * DIN + d) * DSTATE;
        ld4s(&Hinit[o + 0],  h20, h21);
        ld4s(&Hinit[o + 4],  h22, h23);
        ld4s(&Hinit[o + 8],  h24, h25);
        ld4s(&Hinit[o + 12], h26, h27);
    }
    const float Dval = Dp[d];
    const long gbase = ((long)b * L + t0) * DIN + d;
    __syncthreads();
    #pragma unroll 2
    for (int t = 0; t < LC; ++t) {
        float dlt = sDl[t][tid];                  // replaces dp-dot + softplus
        float uu = __half2float(sU[t][tid]);
        float zz = __half2float(sZ[t][tid]);
        float du = dlt * uu;
        f32x2 du2  = (f32x2){du, du};
        f32x2 dlt2 = (f32x2){dlt, dlt};
        f32x2 b0, b1, b2, b3, b4, b5, b6, b7;
        ld4s(&sB[t][0],  b0, b1);
        ld4s(&sB[t][4],  b2, b3);
        ld4s(&sB[t][8],  b4, b5);
        ld4s(&sB[t][12], b6, b7);
        f32x2 c0, c1, c2, c3, c4, c5, c6, c7;
        ld4s(&sC[t][0],  c0, c1);
        ld4s(&sC[t][4],  c2, c3);
        ld4s(&sC[t][8],  c4, c5);
        ld4s(&sC[t][12], c6, c7);
        f32x2 y2a = {0,0}, y2b = {0,0}, y2c = {0,0}, y2d = {0,0};
#define P3K(k, yacc) { f32x2 tt = dlt2 * A2##k; f32x2 a_; \
        a_.x = EXP2(tt.x); a_.y = EXP2(tt.y); \
        h2##k = fma2(h2##k, a_, du2 * b##k); \
        yacc = fma2(h2##k, c##k, yacc); }
        P3K(0, y2a) P3K(1, y2b) P3K(2, y2c) P3K(3, y2d)
        P3K(4, y2a) P3K(5, y2b) P3K(6, y2c) P3K(7, y2d)
#undef P3K
        f32x2 ys = (y2a + y2b) + (y2c + y2d);
        float y = ys.x + ys.y;
        y2h[gbase + t * DIN] = __float2half((y + uu * Dval) * silu_f(zz));
    }
}

// ---------------- LayerNorm over C + transpose to (B,C,L) ----------------
__global__ __launch_bounds__(256)
void ln_kernel(const float* __restrict__ X, const float* __restrict__ gamma,
               const float* __restrict__ beta, float* __restrict__ out)
{
    __shared__ float tile[32][257];
    __shared__ float sMu[32], sRs[32];
    const int l0 = blockIdx.x * 32;
    const int b  = blockIdx.y;
    const int tid = threadIdx.x;
    for (int i = tid; i < 32 * 256; i += 256) {
        int l = i >> 8, c = i & 255;
        tile[l][c] = X[((long)b * L + l0 + l) * CDIM + c];
    }
    __syncthreads();
    {
        int l = tid >> 3, sub = tid & 7;
        float s1 = 0.f, s2 = 0.f;
        for (int c = sub * 32; c < sub * 32 + 32; ++c) {
            float v = tile[l][c];
            s1 += v; s2 += v * v;
        }
        s1 += __shfl_xor(s1, 1); s2 += __shfl_xor(s2, 1);
        s1 += __shfl_xor(s1, 2); s2 += __shfl_xor(s2, 2);
        s1 += __shfl_xor(s1, 4); s2 += __shfl_xor(s2, 4);
        if (sub == 0) {
            float mu = s1 * (1.f / 256.f);
            float var = s2 * (1.f / 256.f) - mu * mu;
            sMu[l] = mu;
            sRs[l] = rsqrtf(var + 1e-5f);
        }
    }
    __syncthreads();
    for (int i = tid; i < 32 * 256; i += 256) {
        int ll = i & 31, c = i >> 5;
        float v = (tile[ll][c] - sMu[ll]) * sRs[ll] * gamma[c] + beta[c];
        out[((long)b * CDIM + c) * L + l0 + ll] = v;
    }
}

extern "C" void kernel_launch(void* const* d_in, const int* in_sizes, int n_in,
                              void* d_out, int out_size, void* d_ws, size_t ws_size,
                              hipStream_t stream)
{
    const float* sp   = (const float*)d_in[0];
    const float* fq   = (const float*)d_in[1];
    const float* Wp   = (const float*)d_in[2];
    const float* bp   = (const float*)d_in[3];
    const float* Win  = (const float*)d_in[4];
    const float* cw   = (const float*)d_in[5];
    const float* cb   = (const float*)d_in[6];
    const float* Wx   = (const float*)d_in[7];
    const float* Wdt  = (const float*)d_in[8];
    const float* bdt  = (const float*)d_in[9];
    const float* Alog = (const float*)d_in[10];
    const float* Dp   = (const float*)d_in[11];
    const float* Wout = (const float*)d_in[12];
    const float* gam  = (const float*)d_in[13];
    const float* bet  = (const float*)d_in[14];
    float* out = (float*)d_out;
    float* ws  = (float*)d_ws;

    const size_t NLD = (size_t)BATCH * L * DIN;   // 8.39M
    const size_t NLC = (size_t)BATCH * L * CDIM;  // 4.19M

    size_t off = 0;
    __half* u16   = (__half*)(ws + off); off += NLD / 2;  // pre-conv u
    __half* u16c  = (__half*)(ws + off); off += NLD / 2;  // post-conv silu(u)
    __half* z16   = (__half*)(ws + off); off += NLD / 2;
    __half* y16   = (__half*)(ws + off); off += NLD / 2;
    __half* xp16  = (__half*)(ws + off); off += NLC / 2;
    float*  xmix  = ws + off; off += NLC;
    float*  dtA   = ws + off; off += (size_t)BATCH * L * DTR;
    float*  Dl    = ws + off; off += NLD;                 // fp32 delta handoff
    __half* wph   = (__half*)(ws + off); off += SZ_WP / 2;
    __half* winh  = (__half*)(ws + off); off += SZ_WIN / 2;
    __half* woh   = (__half*)(ws + off); off += SZ_WO / 2;
    __half* wch   = (__half*)(ws + off); off += SZ_WC / 2;
    float*  Bmb   = ws + off; off += (size_t)BATCH * L * DSTATE;
    float*  Cmb   = ws + off; off += (size_t)BATCH * L * DSTATE;
    float*  Xc    = ws + off; off += (size_t)BATCH * NC * DIN * DSTATE;
    float*  DS    = ws + off; off += (size_t)BATCH * NC * DIN;
    float*  Hout  = ws + off; off += (size_t)BATCH * NC * DIN * DSTATE;

    dim3 blk(256);
    pack_all<<<dim3((SZ_WP + SZ_WIN + SZ_WO + SZ_WC) / 256), blk, 0, stream>>>(
        Wp, Win, Wout, Wx, wph, winh, woh, wch);

    // GEMM1: x_proj = x_cat @ Wp^T + bp  (A fp32 K-major reg-staged; B gload_lds)
    hgemm_g<HEPI_XP, true, 2><<<dim3(BATCH * (L/64) * 4), blk, 0, stream>>>(
        sp, fq, nullptr, wph, bp, nullptr, xp16, nullptr,
        L, CDIM, 2 * CDIM, CDIM, (long)CDIM * L, 4);
    // GEMM2: xz = x_proj @ Win^T -> u16 / z16  (full gload_lds staging)
    hgemm_g<HEPI_UZ, false, 4><<<dim3(BATCH * (L/64) * 8), blk, 0, stream>>>(
        nullptr, nullptr, xp16, winh, nullptr, nullptr, u16, z16,
        L, 2 * DIN, CDIM, 1 << 30, (long)L * CDIM, 8);

    conv_silu_kernel<<<dim3((int)(NLD / 8 / 256)), blk, 0, stream>>>(u16, cw, cb, u16c);
    // D34 rank-16: dbc = u @ Wx^T (N=48: dt|Bm|Cm) -- old kernel (OOB guard)
    hgemm<HEPI_D34, 2><<<dim3(BATCH * (L/64) * 1), blk, 0, stream>>>(
        u16c, wch, dtA, Bmb, Cmb, L, 48, DIN, (long)L * DIN, 1);

    scan_phase1<<<dim3(BATCH * NC * 2), blk, 0, stream>>>(
        dtA, u16c, Bmb, Alog, Wdt, bdt, Xc, DS, Dl);
    scan_phase2<<<dim3(BATCH * DIN * DSTATE / 256), blk, 0, stream>>>(Xc, DS, Alog, Hout);
    scan_phase3<<<dim3(BATCH * NC * 2), blk, 0, stream>>>(
        Dl, u16c, Bmb, Cmb, z16, Alog, Dp, Hout, y16);

    // GEMM5: x_mixed = y2 @ Wout^T  (full gload_lds staging)
    hgemm_g<HEPI_F32, false, 2><<<dim3(BATCH * (L/64) * 4), blk, 0, stream>>>(
        nullptr, nullptr, y16, woh, nullptr, xmix, nullptr, nullptr,
        L, CDIM, DIN, 1 << 30, (long)L * DIN, 4);
    ln_kernel<<<dim3(L / 32, BATCH), blk, 0, stream>>>(xmix, gam, bet, out);
}

// Round 14
// 288.359 us; speedup vs baseline: 1.0643x; 1.0318x over previous
//
#include <hip/hip_runtime.h>
#include <hip/hip_fp16.h>
#include <math.h>

#define L 4096
#define CDIM 256
#define DIN 512
#define DSTATE 16
#define DTR 16
#define BATCH 4

using f32x4  = __attribute__((ext_vector_type(4))) float;
using f32x2  = __attribute__((ext_vector_type(2))) float;
using f16x8  = __attribute__((ext_vector_type(8))) _Float16;

#define LOG2E 1.44269504088896f

#if __has_builtin(__builtin_amdgcn_exp2f)
#define EXP2(x) __builtin_amdgcn_exp2f(x)
#else
#define EXP2(x) __expf((x) * 0.69314718056f)
#endif

__device__ __forceinline__ float silu_f(float x) {
    return __fdividef(x, 1.f + __expf(-x));
}
__device__ __forceinline__ float softplus_fast(float x) {
    return (x > 20.f) ? x : __logf(1.f + __expf(x));
}
__device__ __forceinline__ unsigned pk2h(float a, float b) {
    __half2 h = __floats2half2_rn(a, b);
    return *reinterpret_cast<unsigned*>(&h);
}

// async global->LDS, 16B per lane, dest = wave-uniform base + lane*16
__device__ __forceinline__ void gload_lds16(const void* g, void* l) {
    __builtin_amdgcn_global_load_lds(
        (const __attribute__((address_space(1))) void*)g,
        (__attribute__((address_space(3))) void*)l, 16, 0, 0);
}

// LESSONS (measured, do not repeat):
//  - r1: lgkm-only barrier + depth-2 reg prefetch regressed GEMMs.
//  - r4: trans->VALU conversion regressed scans; delete VALU, keep trans.
//  - r5: 128x128 tile regressed GEMMs (occupancy hides stalls; 64-tile wins).
//  - r6: pk-f32 scan math WORKED (-15%).
//  - r8: gload_lds + LDK32 swizzle WORKED: GEMMs left top-5. 300.6us.
//  - r9: conv vectorization + traffic cut: 297.7us (NC=128, dp in phase3).
//  - r10: occupancy x2 (NC=256) -> phase3 +4% only, total FLAT (traffic cost).
//  - r11: LDS-read elimination -> phase3 UNCHANGED. NOT LDS-pipe-bound.
//  - r12: delta handoff at NC=256: neutral (VALU saved = Dl+NC256 traffic paid).
//  - r13: named-SSA refactor: NULL. Arrays were already in registers.
//  - r14: recombine the two independent wins: NC=128 (less traffic, short
//    phase2) + delta handoff (no dp-dot in phase3; Dl read direct from global).
//    If flat -> practical plateau; declare convergence.
//  - WRITE_SIZE on early dispatches includes harness memset traffic (artifact).

enum { HEPI_XP = 0, HEPI_UZ = 1, HEPI_F32 = 2, HEPI_D34 = 3 };

// ====== hgemm_g: 64-row tiles, global_load_lds staging, LDK=32 + XOR swizzle ======
template<int EPI, bool A_F32KM, int NT>
__global__ __launch_bounds__(256)
void hgemm_g(const float* __restrict__ Af0, const float* __restrict__ Af1,
             const __half* __restrict__ Ah_g, const __half* __restrict__ Bh_g,
             const float* __restrict__ bias,
             float* __restrict__ O0, __half* __restrict__ Oh0, __half* __restrict__ Oh1,
             int M, int N, int K, int kSplit, long strideAb, int nBlk)
{
    constexpr int BM = 64, MT = 2;
    constexpr int BN = 2 * NT * 16;         // 64 or 128
    constexpr int BCH = BN / 64;            // B gload instrs per wave: 1 or 2
    __shared__ __align__(16) _Float16 Ah[2][BM][32];
    __shared__ __align__(16) _Float16 Bh[2][BN][32];
    const int mBlk = M / BM;
    // XCD-sticky swizzle
    const int bid = blockIdx.x;
    const int r = bid & 7, q = bid >> 3;
    const int ni = q % nBlk;
    const int mg = (q / nBlk) * 8 + r;
    const int b = mg / mBlk, m_idx = mg - b * mBlk;
    const int n0 = ni * BN, m0 = m_idx * BM;
    const int tid  = threadIdx.x;
    const int lane = tid & 63;
    const int w    = tid >> 6;
    const int wr   = w >> 1, wc = w & 1;
    const int lrow = lane & 15;
    const int loct = lane >> 4;
    // gload source mapping: lane l -> row-in-chunk l>>2, swizzled k-octet kc
    const int gsub = lane >> 2;
    const int kc   = (lane & 3) ^ ((lane >> 3) & 3);
    // read-side swizzled column (f16 units), lane-constant
    const int swc  = (loct ^ ((lrow >> 1) & 3)) * 8;

    f32x4 acc[MT][NT];
    #pragma unroll
    for (int i = 0; i < MT; ++i)
        #pragma unroll
        for (int j = 0; j < NT; ++j)
            acc[i][j] = (f32x4){0.f, 0.f, 0.f, 0.f};

    float va[8];
    auto loadA32 = [&](int kk) {        // GEMM1: fp32 K-major A -> regs (needs cvt)
        if constexpr (A_F32KM) {
            int m = tid & 63, ks = tid >> 6;
            #pragma unroll
            for (int j = 0; j < 8; ++j) {
                int kg = kk + ks * 8 + j;
                const float* Ap; int kl;
                if (kg < kSplit) { Ap = Af0; kl = kg; } else { Ap = Af1; kl = kg - kSplit; }
                va[j] = Ap[(long)b * strideAb + (long)kl * M + m0 + m];
            }
        }
    };
    auto storeA32 = [&](int buf) {      // swizzled ds_write (matches read XOR)
        if constexpr (A_F32KM) {
            int m = tid & 63, ks = tid >> 6;
            int ksw = (ks ^ ((m >> 1) & 3)) * 8;
            uint4 h;
            h.x = pk2h(va[0], va[1]);
            h.y = pk2h(va[2], va[3]);
            h.z = pk2h(va[4], va[5]);
            h.w = pk2h(va[6], va[7]);
            *(uint4*)&Ah[buf][m][ksw] = h;
        }
    };
    auto stageA = [&](int kk, int buf) {
        if constexpr (!A_F32KM) {
            const __half* src = Ah_g + (long)b * strideAb +
                                (long)(m0 + w * 16 + gsub) * K + kk + kc * 8;
            gload_lds16(src, &Ah[buf][w * 16][0]);
        }
    };
    auto stageB = [&](int kk, int buf) {
        #pragma unroll
        for (int p = 0; p < BCH; ++p) {
            int ch = w * BCH + p;       // 16-row chunk index
            const __half* src = Bh_g + (long)(n0 + ch * 16 + gsub) * K + kk + kc * 8;
            gload_lds16(src, &Bh[buf][ch * 16][0]);
        }
    };

    loadA32(0);
    stageA(0, 0); stageB(0, 0);
    storeA32(0);
    __syncthreads();                    // drains vmcnt -> gloads landed
    int cur = 0;
    for (int kk = 0; kk < K; kk += 32) {
        const bool more = (kk + 32 < K);
        if (more) {
            loadA32(kk + 32);
            stageA(kk + 32, cur ^ 1);   // async, direct to LDS buf^1
            stageB(kk + 32, cur ^ 1);
        }
        f16x8 bh[NT];
        #pragma unroll
        for (int nt = 0; nt < NT; ++nt)
            bh[nt] = *(const f16x8*)&Bh[cur][wc*NT*16 + nt*16 + lrow][swc];
        #pragma unroll
        for (int mt = 0; mt < MT; ++mt) {
            f16x8 ah = *(const f16x8*)&Ah[cur][wr*MT*16 + mt*16 + lrow][swc];
            #pragma unroll
            for (int nt = 0; nt < NT; ++nt)
                acc[mt][nt] = __builtin_amdgcn_mfma_f32_16x16x32_f16(ah, bh[nt], acc[mt][nt], 0, 0, 0);
        }
        if (more) {
            storeA32(cur ^ 1);
            __syncthreads();            // ONE barrier per k-iter (r0 schedule)
            cur ^= 1;
        }
    }
    // epilogue: C/D col=lane&15, row=(lane>>4)*4+reg
    #pragma unroll
    for (int mt = 0; mt < MT; ++mt) {
        #pragma unroll
        for (int r4 = 0; r4 < 4; ++r4) {
            int m = m0 + wr*MT*16 + mt * 16 + loct * 4 + r4;
            long rowb = (long)b * M + m;
            #pragma unroll
            for (int nt = 0; nt < NT; ++nt) {
                int n = n0 + wc*NT*16 + nt * 16 + lrow;
                float v = acc[mt][nt][r4];
                if constexpr (EPI == HEPI_XP) {
                    Oh0[rowb * N + n] = __float2half(v + bias[n]);
                } else if constexpr (EPI == HEPI_UZ) {
                    if (n < DIN) Oh0[rowb * DIN + n] = __float2half(v);
                    else         Oh1[rowb * DIN + (n - DIN)] = __float2half(v);
                } else {
                    O0[rowb * N + n] = v;
                }
            }
        }
    }
}

#define LDK 40
// ====== old reg-staged hgemm (LDK=40): kept ONLY for D34 (needs OOB zero-guard) ===
template<int EPI, int NT>
__global__ __launch_bounds__(256)
void hgemm(const __half* __restrict__ Ah_g, const __half* __restrict__ Bh_g,
           float* __restrict__ O0, float* __restrict__ Ob, float* __restrict__ Oc,
           int M, int N, int K, long strideAb, int nBlk)
{
    constexpr int BM = 64, MT = 2;
    constexpr int BN = 2 * NT * 16;
    constexpr int BSEG = BN / 64;
    __shared__ __align__(16) _Float16 Ah[2][BM][LDK];
    __shared__ __align__(16) _Float16 Bh[2][BN][LDK];
    const int mBlk = M / BM;
    const int bid = blockIdx.x;
    const int r = bid & 7, q = bid >> 3;
    const int ni = q % nBlk;
    const int mg = (q / nBlk) * 8 + r;
    const int b = mg / mBlk, m_idx = mg - b * mBlk;
    const int n0 = ni * BN, m0 = m_idx * BM;
    const int tid  = threadIdx.x;
    const int lane = tid & 63;
    const int w    = tid >> 6;
    const int wr   = w >> 1, wc = w & 1;
    const int lrow = lane & 15;
    const int loct = lane >> 4;

    f32x4 acc[MT][NT];
    #pragma unroll
    for (int i = 0; i < MT; ++i)
        #pragma unroll
        for (int j = 0; j < NT; ++j)
            acc[i][j] = (f32x4){0.f, 0.f, 0.f, 0.f};

    const int sOct = tid & 3, sRow = tid >> 2;
    uint4 pa, pb[BSEG];

    auto loadA = [&](int kk) {
        pa = *(const uint4*)(Ah_g + (long)b * strideAb +
                             (long)(m0 + sRow) * K + kk + sOct * 8);
    };
    auto loadB = [&](int kk) {
        #pragma unroll
        for (int p = 0; p < BSEG; ++p) {
            int ng = n0 + sRow + p * 64;
            if (ng >= N) pb[p] = make_uint4(0, 0, 0, 0);
            else pb[p] = *(const uint4*)(Bh_g + (long)ng * K + kk + sOct * 8);
        }
    };
    auto storeAB = [&](int buf) {
        *(uint4*)&Ah[buf][sRow][sOct * 8] = pa;
        #pragma unroll
        for (int p = 0; p < BSEG; ++p)
            *(uint4*)&Bh[buf][sRow + p * 64][sOct * 8] = pb[p];
    };

    loadA(0); loadB(0);
    storeAB(0);
    __syncthreads();
    int cur = 0;
    for (int kk = 0; kk < K; kk += 32) {
        const bool more = (kk + 32 < K);
        if (more) { loadA(kk + 32); loadB(kk + 32); }
        f16x8 bh[NT];
        #pragma unroll
        for (int nt = 0; nt < NT; ++nt)
            bh[nt] = *(const f16x8*)&Bh[cur][wc*NT*16 + nt*16 + lrow][loct*8];
        #pragma unroll
        for (int mt = 0; mt < MT; ++mt) {
            f16x8 ah = *(const f16x8*)&Ah[cur][wr*MT*16 + mt*16 + lrow][loct*8];
            #pragma unroll
            for (int nt = 0; nt < NT; ++nt)
                acc[mt][nt] = __builtin_amdgcn_mfma_f32_16x16x32_f16(ah, bh[nt], acc[mt][nt], 0, 0, 0);
        }
        if (more) {
            storeAB(cur ^ 1);
            __syncthreads();
            cur ^= 1;
        }
    }
    #pragma unroll
    for (int mt = 0; mt < MT; ++mt) {
        #pragma unroll
        for (int r4 = 0; r4 < 4; ++r4) {
            int m = m0 + wr*MT*16 + mt * 16 + loct * 4 + r4;
            long rowb = (long)b * M + m;
            #pragma unroll
            for (int nt = 0; nt < NT; ++nt) {
                int n = n0 + wc*NT*16 + nt * 16 + lrow;
                float v = acc[mt][nt][r4];
                if (n < DTR)           O0[rowb * DTR + n] = v;
                else if (n < 2 * DTR)  Ob[rowb * 16 + (n - DTR)] = v;
                else if (n < 48)       Oc[rowb * 16 + (n - 32)] = v;
            }
        }
    }
}

// ---------------- weight prep: fp16 casts ---------
#define SZ_WP  131072
#define SZ_WIN 262144
#define SZ_WO  131072
#define SZ_WC  24576
__global__ __launch_bounds__(256)
void pack_all(const float* __restrict__ Wp, const float* __restrict__ Win,
              const float* __restrict__ Wout, const float* __restrict__ Wx,
              __half* __restrict__ wph, __half* __restrict__ winh,
              __half* __restrict__ woh, __half* __restrict__ wch)
{
    int i = blockIdx.x * 256 + threadIdx.x;
    if (i < SZ_WP) { wph[i] = __float2half(Wp[i]); return; }
    i -= SZ_WP;
    if (i < SZ_WIN) { winh[i] = __float2half(Win[i]); return; }
    i -= SZ_WIN;
    if (i < SZ_WO) { woh[i] = __float2half(Wout[i]); return; }
    i -= SZ_WO;
    if (i < SZ_WC) wch[i] = __float2half(Wx[i]);   // (48, 512) row-major
}

// ------- depthwise causal conv (k=4) + silu: VECTORIZED 8 d's/thread (G13) -------
__global__ __launch_bounds__(256)
void conv_silu_kernel(const __half* __restrict__ u_pre, const float* __restrict__ cw,
                      const float* __restrict__ cb, __half* __restrict__ u)
{
    long gid = (long)blockIdx.x * 256 + threadIdx.x;   // NLD/8 threads
    const int dv = (int)(gid & 63);                    // d0 = dv*8
    const long bl = gid >> 6;                          // b*L + l
    const int l = (int)(bl & (L - 1));
    const long brow = bl - l;
    const int d0 = dv * 8;

    float acc[8];
    {
        float4 c0 = *(const float4*)&cb[d0];
        float4 c1 = *(const float4*)&cb[d0 + 4];
        acc[0]=c0.x; acc[1]=c0.y; acc[2]=c0.z; acc[3]=c0.w;
        acc[4]=c1.x; acc[5]=c1.y; acc[6]=c1.z; acc[7]=c1.w;
    }
    float4 wrow[8];                                    // cw rows (hot 8KB in L2)
    #pragma unroll
    for (int e = 0; e < 8; ++e) wrow[e] = *(const float4*)&cw[(d0 + e) * 4];

    #pragma unroll
    for (int j = 0; j < 4; ++j) {
        int li = l - 3 + j;                            // wave-uniform branch
        if (li >= 0) {
            uint4 raw = *(const uint4*)(u_pre + (brow + li) * DIN + d0);
            const __half2* h2 = (const __half2*)&raw;
            #pragma unroll
            for (int e = 0; e < 4; ++e) {
                float2 f = __half22float2(h2[e]);
                float w0 = (j == 0) ? wrow[2*e].x : (j == 1) ? wrow[2*e].y
                         : (j == 2) ? wrow[2*e].z : wrow[2*e].w;
                float w1 = (j == 0) ? wrow[2*e+1].x : (j == 1) ? wrow[2*e+1].y
                         : (j == 2) ? wrow[2*e+1].z : wrow[2*e+1].w;
                acc[2*e]   = fmaf(f.x, w0, acc[2*e]);
                acc[2*e+1] = fmaf(f.y, w1, acc[2*e+1]);
            }
        }
    }
    uint4 st;
    st.x = pk2h(silu_f(acc[0]), silu_f(acc[1]));
    st.y = pk2h(silu_f(acc[2]), silu_f(acc[3]));
    st.z = pk2h(silu_f(acc[4]), silu_f(acc[5]));
    st.w = pk2h(silu_f(acc[6]), silu_f(acc[7]));
    *(uint4*)(u + bl * DIN + d0) = st;
}

// ---------------- chunked parallel selective scan, d-per-lane ----------------
// r14: NC=128 (r9 traffic/phase2 profile) + r12 delta handoff (no dp-dot in
// phase3; Dl read per-t directly from global -- per-lane coalesced, VMEM idle).
#define NC 128
#define LC (L / NC)

__device__ __forceinline__ f32x2 fma2(f32x2 a, f32x2 b, f32x2 c) {
    return __builtin_elementwise_fma(a, b, c);
}
__device__ __forceinline__ void ld4s(const float* p, f32x2& lo, f32x2& hi) {
    f32x4 v = *(const f32x4*)p;
    lo = __builtin_shufflevector(v, v, 0, 1);
    hi = __builtin_shufflevector(v, v, 2, 3);
}

#define LDA2(qi, lo, hi) { \
    float4 v_ = *(const float4*)&A_log[d * DSTATE + (qi) * 4]; \
    lo = (f32x2){-__expf(v_.x) * LOG2E, -__expf(v_.y) * LOG2E}; \
    hi = (f32x2){-__expf(v_.z) * LOG2E, -__expf(v_.w) * LOG2E}; }

#define LDW2(qi, lo, hi) { \
    float4 v_ = *(const float4*)&Wdt[d * DTR + (qi) * 4]; \
    lo = (f32x2){v_.x, v_.y}; hi = (f32x2){v_.z, v_.w}; }

__global__ __launch_bounds__(256)
void scan_phase1(const float* __restrict__ dtA, const __half* __restrict__ u,
                 const float* __restrict__ Bm, const float* __restrict__ A_log,
                 const float* __restrict__ Wdt, const float* __restrict__ bdt,
                 float* __restrict__ Xc, float* __restrict__ DS,
                 float* __restrict__ Dl)
{
    __shared__ float sB[LC][DSTATE];
    __shared__ float sDt[LC][DTR];
    __shared__ __half sU[LC][256];
    const int gd = blockIdx.x & 1;
    const int c  = (blockIdx.x >> 1) & (NC - 1);
    const int b  = blockIdx.x >> 8;
    const int tid = threadIdx.x;
    const int d  = gd * 256 + tid;
    const int t0 = c * LC;
    f32x2 A20, A21, A22, A23, A24, A25, A26, A27;
    LDA2(0, A20, A21) LDA2(1, A22, A23) LDA2(2, A24, A25) LDA2(3, A26, A27)
    f32x2 W0, W1, W2, W3, W4, W5, W6, W7;
    LDW2(0, W0, W1) LDW2(1, W2, W3) LDW2(2, W4, W5) LDW2(3, W6, W7)
    const float bd = bdt[d];
    {
        const __half* ub = u + ((long)b * L + t0) * DIN + gd * 256;
        #pragma unroll
        for (int j = 0; j < 4; ++j) {
            int i = tid + j * 256;            // 1024 float4s = 32 rows x 32
            int t = i >> 5, col = (i & 31) * 8;
            *(float4*)&sU[t][col] = *(const float4*)&ub[(long)t * DIN + col];
        }
        if (tid < 128) {
            const float* Bb = Bm  + ((long)b * L + t0) * DSTATE;
            const float* Db = dtA + ((long)b * L + t0) * DTR;
            *(float4*)&((float*)sB)[tid * 4]  = *(const float4*)&Bb[tid * 4];
            *(float4*)&((float*)sDt)[tid * 4] = *(const float4*)&Db[tid * 4];
        }
    }
    __syncthreads();
    f32x2 X20 = {0,0}, X21 = {0,0}, X22 = {0,0}, X23 = {0,0};
    f32x2 X24 = {0,0}, X25 = {0,0}, X26 = {0,0}, X27 = {0,0};
    float dsum = 0.f;
    const long gbase = ((long)b * L + t0) * DIN + d;
    #pragma unroll 2
    for (int t = 0; t < LC; ++t) {
        f32x2 q0, q1, q2, q3, q4, q5, q6, q7;
        ld4s(&sDt[t][0],  q0, q1);
        ld4s(&sDt[t][4],  q2, q3);
        ld4s(&sDt[t][8],  q4, q5);
        ld4s(&sDt[t][12], q6, q7);
        f32x2 dpA = q0 * W0, dpB = q1 * W1;
        dpA = fma2(q2, W2, dpA); dpB = fma2(q3, W3, dpB);
        dpA = fma2(q4, W4, dpA); dpB = fma2(q5, W5, dpB);
        dpA = fma2(q6, W6, dpA); dpB = fma2(q7, W7, dpB);
        float dlt = softplus_fast(((dpA.x + dpA.y) + (dpB.x + dpB.y)) + bd);
        Dl[gbase + (long)t * DIN] = dlt;          // fp32 handoff to phase3
        dsum += dlt;
        float du = dlt * __half2float(sU[t][tid]);
        f32x2 du2  = (f32x2){du, du};
        f32x2 dlt2 = (f32x2){dlt, dlt};
        f32x2 b0, b1, b2, b3, b4, b5, b6, b7;
        ld4s(&sB[t][0],  b0, b1);
        ld4s(&sB[t][4],  b2, b3);
        ld4s(&sB[t][8],  b4, b5);
        ld4s(&sB[t][12], b6, b7);
#define P1K(k) { f32x2 tt = dlt2 * A2##k; f32x2 a_; \
        a_.x = EXP2(tt.x); a_.y = EXP2(tt.y); \
        X2##k = fma2(a_, X2##k, du2 * b##k); }
        P1K(0) P1K(1) P1K(2) P1K(3) P1K(4) P1K(5) P1K(6) P1K(7)
#undef P1K
    }
    long o = (((long)b * NC + c) * DIN + d) * DSTATE;
    *(float4*)&Xc[o + 0]  = make_float4(X20.x, X20.y, X21.x, X21.y);
    *(float4*)&Xc[o + 4]  = make_float4(X22.x, X22.y, X23.x, X23.y);
    *(float4*)&Xc[o + 8]  = make_float4(X24.x, X24.y, X25.x, X25.y);
    *(float4*)&Xc[o + 12] = make_float4(X26.x, X26.y, X27.x, X27.y);
    DS[((long)b * NC + c) * DIN + d] = dsum;
}

// cross-chunk scan: 32768 independent series; pure-ILP kernel.
__global__ __launch_bounds__(256)
void scan_phase2(const float* __restrict__ Xc, const float* __restrict__ DS,
                 const float* __restrict__ A_log, float* __restrict__ Hout)
{
    int lane = blockIdx.x * 256 + threadIdx.x;   // 32768 total
    int b = lane >> 13;
    int rem = lane & 8191;                       // d*16 + s
    int d = rem >> 4;
    const float Ar = -__expf(A_log[rem]) * LOG2E;
    const long cs = (long)DIN * DSTATE;
    const long xb = (long)b * NC * cs + rem;
    const long db = (long)b * NC * DIN + d;
    float h = 0.f;
    float xc_[8], ts_[8], nx_[8], nt_[8];
    auto ldx = [&](int c) { return Xc[xb + (long)c * cs]; };
    auto ldt = [&](int c) { return DS[db + (long)c * DIN]; };
    #pragma unroll
    for (int j = 0; j < 8; ++j) { xc_[j] = ldx(j);     ts_[j] = ldt(j); }
    #pragma unroll
    for (int j = 0; j < 8; ++j) { nx_[j] = ldx(8 + j); nt_[j] = ldt(8 + j); }
    for (int c = 0; c < NC; c += 8) {
        #pragma unroll
        for (int j = 0; j < 8; ++j) {
            Hout[xb + (long)(c + j) * cs] = h;
            h = fmaf(EXP2(ts_[j] * Ar), h, xc_[j]);
        }
        #pragma unroll
        for (int j = 0; j < 8; ++j) { xc_[j] = nx_[j]; ts_[j] = nt_[j]; }
        if (c + 16 < NC) {
            #pragma unroll
            for (int j = 0; j < 8; ++j) {
                nx_[j] = ldx(c + 16 + j);
                nt_[j] = ldt(c + 16 + j);
            }
        }
    }
}

__global__ __launch_bounds__(256)
void scan_phase3(const float* __restrict__ Dl, const __half* __restrict__ u,
                 const float* __restrict__ Bm, const float* __restrict__ Cm,
                 const __half* __restrict__ z, const float* __restrict__ A_log,
                 const float* __restrict__ Dp, const float* __restrict__ Hinit,
                 __half* __restrict__ y2h)
{
    __shared__ float sB[LC][DSTATE], sC[LC][DSTATE];
    __shared__ __half sU[LC][256];
    __shared__ __half sZ[LC][256];
    const int gd = blockIdx.x & 1;
    const int c  = (blockIdx.x >> 1) & (NC - 1);
    const int b  = blockIdx.x >> 8;
    const int tid = threadIdx.x;
    const int d  = gd * 256 + tid;
    const int t0 = c * LC;
    f32x2 A20, A21, A22, A23, A24, A25, A26, A27;
    LDA2(0, A20, A21) LDA2(1, A22, A23) LDA2(2, A24, A25) LDA2(3, A26, A27)
    {
        const __half* ub = u  + ((long)b * L + t0) * DIN + gd * 256;
        const __half* zb = z  + ((long)b * L + t0) * DIN + gd * 256;
        #pragma unroll
        for (int j = 0; j < 4; ++j) {
            int i = tid + j * 256;
            int t = i >> 5, col = (i & 31) * 8;
            *(float4*)&sU[t][col] = *(const float4*)&ub[(long)t * DIN + col];
            *(float4*)&sZ[t][col] = *(const float4*)&zb[(long)t * DIN + col];
        }
        if (tid < 128) {
            const float* Bb = Bm  + ((long)b * L + t0) * DSTATE;
            const float* Cb = Cm  + ((long)b * L + t0) * DSTATE;
            *(float4*)&((float*)sB)[tid * 4]  = *(const float4*)&Bb[tid * 4];
            *(float4*)&((float*)sC)[tid * 4]  = *(const float4*)&Cb[tid * 4];
        }
    }
    f32x2 h20, h21, h22, h23, h24, h25, h26, h27;
    {
        long o = (((long)b * NC + c) * DIN + d) * DSTATE;
        ld4s(&Hinit[o + 0],  h20, h21);
        ld4s(&Hinit[o + 4],  h22, h23);
        ld4s(&Hinit[o + 8],  h24, h25);
        ld4s(&Hinit[o + 12], h26, h27);
    }
    const float Dval = Dp[d];
    const long gbase = ((long)b * L + t0) * DIN + d;
    __syncthreads();
    #pragma unroll 2
    for (int t = 0; t < LC; ++t) {
        float dlt = Dl[gbase + (long)t * DIN];    // per-lane coalesced global read
        float uu = __half2float(sU[t][tid]);
        float zz = __half2float(sZ[t][tid]);
        float du = dlt * uu;
        f32x2 du2  = (f32x2){du, du};
        f32x2 dlt2 = (f32x2){dlt, dlt};
        f32x2 b0, b1, b2, b3, b4, b5, b6, b7;
        ld4s(&sB[t][0],  b0, b1);
        ld4s(&sB[t][4],  b2, b3);
        ld4s(&sB[t][8],  b4, b5);
        ld4s(&sB[t][12], b6, b7);
        f32x2 c0, c1, c2, c3, c4, c5, c6, c7;
        ld4s(&sC[t][0],  c0, c1);
        ld4s(&sC[t][4],  c2, c3);
        ld4s(&sC[t][8],  c4, c5);
        ld4s(&sC[t][12], c6, c7);
        f32x2 y2a = {0,0}, y2b = {0,0}, y2c = {0,0}, y2d = {0,0};
#define P3K(k, yacc) { f32x2 tt = dlt2 * A2##k; f32x2 a_; \
        a_.x = EXP2(tt.x); a_.y = EXP2(tt.y); \
        h2##k = fma2(h2##k, a_, du2 * b##k); \
        yacc = fma2(h2##k, c##k, yacc); }
        P3K(0, y2a) P3K(1, y2b) P3K(2, y2c) P3K(3, y2d)
        P3K(4, y2a) P3K(5, y2b) P3K(6, y2c) P3K(7, y2d)
#undef P3K
        f32x2 ys = (y2a + y2b) + (y2c + y2d);
        float y = ys.x + ys.y;
        y2h[gbase + t * DIN] = __float2half((y + uu * Dval) * silu_f(zz));
    }
}

// ---------------- LayerNorm over C + transpose to (B,C,L) ----------------
__global__ __launch_bounds__(256)
void ln_kernel(const float* __restrict__ X, const float* __restrict__ gamma,
               const float* __restrict__ beta, float* __restrict__ out)
{
    __shared__ float tile[32][257];
    __shared__ float sMu[32], sRs[32];
    const int l0 = blockIdx.x * 32;
    const int b  = blockIdx.y;
    const int tid = threadIdx.x;
    for (int i = tid; i < 32 * 256; i += 256) {
        int l = i >> 8, c = i & 255;
        tile[l][c] = X[((long)b * L + l0 + l) * CDIM + c];
    }
    __syncthreads();
    {
        int l = tid >> 3, sub = tid & 7;
        float s1 = 0.f, s2 = 0.f;
        for (int c = sub * 32; c < sub * 32 + 32; ++c) {
            float v = tile[l][c];
            s1 += v; s2 += v * v;
        }
        s1 += __shfl_xor(s1, 1); s2 += __shfl_xor(s2, 1);
        s1 += __shfl_xor(s1, 2); s2 += __shfl_xor(s2, 2);
        s1 += __shfl_xor(s1, 4); s2 += __shfl_xor(s2, 4);
        if (sub == 0) {
            float mu = s1 * (1.f / 256.f);
            float var = s2 * (1.f / 256.f) - mu * mu;
            sMu[l] = mu;
            sRs[l] = rsqrtf(var + 1e-5f);
        }
    }
    __syncthreads();
    for (int i = tid; i < 32 * 256; i += 256) {
        int ll = i & 31, c = i >> 5;
        float v = (tile[ll][c] - sMu[ll]) * sRs[ll] * gamma[c] + beta[c];
        out[((long)b * CDIM + c) * L + l0 + ll] = v;
    }
}

extern "C" void kernel_launch(void* const* d_in, const int* in_sizes, int n_in,
                              void* d_out, int out_size, void* d_ws, size_t ws_size,
                              hipStream_t stream)
{
    const float* sp   = (const float*)d_in[0];
    const float* fq   = (const float*)d_in[1];
    const float* Wp   = (const float*)d_in[2];
    const float* bp   = (const float*)d_in[3];
    const float* Win  = (const float*)d_in[4];
    const float* cw   = (const float*)d_in[5];
    const float* cb   = (const float*)d_in[6];
    const float* Wx   = (const float*)d_in[7];
    const float* Wdt  = (const float*)d_in[8];
    const float* bdt  = (const float*)d_in[9];
    const float* Alog = (const float*)d_in[10];
    const float* Dp   = (const float*)d_in[11];
    const float* Wout = (const float*)d_in[12];
    const float* gam  = (const float*)d_in[13];
    const float* bet  = (const float*)d_in[14];
    float* out = (float*)d_out;
    float* ws  = (float*)d_ws;

    const size_t NLD = (size_t)BATCH * L * DIN;   // 8.39M
    const size_t NLC = (size_t)BATCH * L * CDIM;  // 4.19M

    size_t off = 0;
    __half* u16   = (__half*)(ws + off); off += NLD / 2;  // pre-conv u
    __half* u16c  = (__half*)(ws + off); off += NLD / 2;  // post-conv silu(u)
    __half* z16   = (__half*)(ws + off); off += NLD / 2;
    __half* y16   = (__half*)(ws + off); off += NLD / 2;
    __half* xp16  = (__half*)(ws + off); off += NLC / 2;
    float*  xmix  = ws + off; off += NLC;
    float*  dtA   = ws + off; off += (size_t)BATCH * L * DTR;
    float*  Dl    = ws + off; off += NLD;                 // fp32 delta handoff
    __half* wph   = (__half*)(ws + off); off += SZ_WP / 2;
    __half* winh  = (__half*)(ws + off); off += SZ_WIN / 2;
    __half* woh   = (__half*)(ws + off); off += SZ_WO / 2;
    __half* wch   = (__half*)(ws + off); off += SZ_WC / 2;
    float*  Bmb   = ws + off; off += (size_t)BATCH * L * DSTATE;
    float*  Cmb   = ws + off; off += (size_t)BATCH * L * DSTATE;
    float*  Xc    = ws + off; off += (size_t)BATCH * NC * DIN * DSTATE;
    float*  DS    = ws + off; off += (size_t)BATCH * NC * DIN;
    float*  Hout  = ws + off; off += (size_t)BATCH * NC * DIN * DSTATE;

    dim3 blk(256);
    pack_all<<<dim3((SZ_WP + SZ_WIN + SZ_WO + SZ_WC) / 256), blk, 0, stream>>>(
        Wp, Win, Wout, Wx, wph, winh, woh, wch);

    // GEMM1: x_proj = x_cat @ Wp^T + bp  (A fp32 K-major reg-staged; B gload_lds)
    hgemm_g<HEPI_XP, true, 2><<<dim3(BATCH * (L/64) * 4), blk, 0, stream>>>(
        sp, fq, nullptr, wph, bp, nullptr, xp16, nullptr,
        L, CDIM, 2 * CDIM, CDIM, (long)CDIM * L, 4);
    // GEMM2: xz = x_proj @ Win^T -> u16 / z16  (full gload_lds staging)
    hgemm_g<HEPI_UZ, false, 4><<<dim3(BATCH * (L/64) * 8), blk, 0, stream>>>(
        nullptr, nullptr, xp16, winh, nullptr, nullptr, u16, z16,
        L, 2 * DIN, CDIM, 1 << 30, (long)L * CDIM, 8);

    conv_silu_kernel<<<dim3((int)(NLD / 8 / 256)), blk, 0, stream>>>(u16, cw, cb, u16c);
    // D34 rank-16: dbc = u @ Wx^T (N=48: dt|Bm|Cm) -- old kernel (OOB guard)
    hgemm<HEPI_D34, 2><<<dim3(BATCH * (L/64) * 1), blk, 0, stream>>>(
        u16c, wch, dtA, Bmb, Cmb, L, 48, DIN, (long)L * DIN, 1);

    scan_phase1<<<dim3(BATCH * NC * 2), blk, 0, stream>>>(
        dtA, u16c, Bmb, Alog, Wdt, bdt, Xc, DS, Dl);
    scan_phase2<<<dim3(BATCH * DIN * DSTATE / 256), blk, 0, stream>>>(Xc, DS, Alog, Hout);
    scan_phase3<<<dim3(BATCH * NC * 2), blk, 0, stream>>>(
        Dl, u16c, Bmb, Cmb, z16, Alog, Dp, Hout, y16);

    // GEMM5: x_mixed = y2 @ Wout^T  (full gload_lds staging)
    hgemm_g<HEPI_F32, false, 2><<<dim3(BATCH * (L/64) * 4), blk, 0, stream>>>(
        nullptr, nullptr, y16, woh, nullptr, xmix, nullptr, nullptr,
        L, CDIM, DIN, 1 << 30, (long)L * DIN, 4);
    ln_kernel<<<dim3(L / 32, BATCH), blk, 0, stream>>>(xmix, gam, bet, out);
}

// Round 15
// 287.677 us; speedup vs baseline: 1.0668x; 1.0024x over previous
//
#include <hip/hip_runtime.h>
#include <hip/hip_fp16.h>
#include <math.h>

#define L 4096
#define CDIM 256
#define DIN 512
#define DSTATE 16
#define DTR 16
#define BATCH 4

using f32x4  = __attribute__((ext_vector_type(4))) float;
using f32x2  = __attribute__((ext_vector_type(2))) float;
using f16x8  = __attribute__((ext_vector_type(8))) _Float16;

#define LOG2E 1.44269504088896f

#if __has_builtin(__builtin_amdgcn_exp2f)
#define EXP2(x) __builtin_amdgcn_exp2f(x)
#else
#define EXP2(x) __expf((x) * 0.69314718056f)
#endif

__device__ __forceinline__ float silu_f(float x) {
    return __fdividef(x, 1.f + __expf(-x));
}
__device__ __forceinline__ float softplus_fast(float x) {
    return (x > 20.f) ? x : __logf(1.f + __expf(x));
}
__device__ __forceinline__ unsigned pk2h(float a, float b) {
    __half2 h = __floats2half2_rn(a, b);
    return *reinterpret_cast<unsigned*>(&h);
}

// async global->LDS, 16B per lane, dest = wave-uniform base + lane*16
__device__ __forceinline__ void gload_lds16(const void* g, void* l) {
    __builtin_amdgcn_global_load_lds(
        (const __attribute__((address_space(1))) void*)g,
        (__attribute__((address_space(3))) void*)l, 16, 0, 0);
}

// LESSONS (measured, do not repeat):
//  - r1: lgkm-only barrier + depth-2 reg prefetch regressed GEMMs.
//  - r4: trans->VALU conversion regressed scans; delete VALU, keep trans.
//  - r5: 128x128 tile regressed GEMMs (occupancy hides stalls; 64-tile wins).
//  - r6: pk-f32 scan math WORKED (-15%).
//  - r8: gload_lds + LDK32 swizzle WORKED: GEMMs left top-5. 300.6us.
//  - r9: conv vectorization + traffic cut: 297.7us.
//  - r10/r11/r13: occupancy/LDS-elim/SSA all null -> scans latency-bound.
//    (VALUBusy is CU-level: per-SIMD VALU util ~15%, not 60%.)
//  - r12: delta handoff at NC=256 neutral; r14: NC=128 + handoff = 288.4us BEST.
//  - r15: batch phase3's per-t global Dl read (groups of 8, phase2 pattern) to
//    hide L2 latency. If flat -> declare practical convergence.
//  - WRITE_SIZE on early dispatches includes harness memset traffic (artifact).

enum { HEPI_XP = 0, HEPI_UZ = 1, HEPI_F32 = 2, HEPI_D34 = 3 };

// ====== hgemm_g: 64-row tiles, global_load_lds staging, LDK=32 + XOR swizzle ======
template<int EPI, bool A_F32KM, int NT>
__global__ __launch_bounds__(256)
void hgemm_g(const float* __restrict__ Af0, const float* __restrict__ Af1,
             const __half* __restrict__ Ah_g, const __half* __restrict__ Bh_g,
             const float* __restrict__ bias,
             float* __restrict__ O0, __half* __restrict__ Oh0, __half* __restrict__ Oh1,
             int M, int N, int K, int kSplit, long strideAb, int nBlk)
{
    constexpr int BM = 64, MT = 2;
    constexpr int BN = 2 * NT * 16;         // 64 or 128
    constexpr int BCH = BN / 64;            // B gload instrs per wave: 1 or 2
    __shared__ __align__(16) _Float16 Ah[2][BM][32];
    __shared__ __align__(16) _Float16 Bh[2][BN][32];
    const int mBlk = M / BM;
    // XCD-sticky swizzle
    const int bid = blockIdx.x;
    const int r = bid & 7, q = bid >> 3;
    const int ni = q % nBlk;
    const int mg = (q / nBlk) * 8 + r;
    const int b = mg / mBlk, m_idx = mg - b * mBlk;
    const int n0 = ni * BN, m0 = m_idx * BM;
    const int tid  = threadIdx.x;
    const int lane = tid & 63;
    const int w    = tid >> 6;
    const int wr   = w >> 1, wc = w & 1;
    const int lrow = lane & 15;
    const int loct = lane >> 4;
    // gload source mapping: lane l -> row-in-chunk l>>2, swizzled k-octet kc
    const int gsub = lane >> 2;
    const int kc   = (lane & 3) ^ ((lane >> 3) & 3);
    // read-side swizzled column (f16 units), lane-constant
    const int swc  = (loct ^ ((lrow >> 1) & 3)) * 8;

    f32x4 acc[MT][NT];
    #pragma unroll
    for (int i = 0; i < MT; ++i)
        #pragma unroll
        for (int j = 0; j < NT; ++j)
            acc[i][j] = (f32x4){0.f, 0.f, 0.f, 0.f};

    float va[8];
    auto loadA32 = [&](int kk) {        // GEMM1: fp32 K-major A -> regs (needs cvt)
        if constexpr (A_F32KM) {
            int m = tid & 63, ks = tid >> 6;
            #pragma unroll
            for (int j = 0; j < 8; ++j) {
                int kg = kk + ks * 8 + j;
                const float* Ap; int kl;
                if (kg < kSplit) { Ap = Af0; kl = kg; } else { Ap = Af1; kl = kg - kSplit; }
                va[j] = Ap[(long)b * strideAb + (long)kl * M + m0 + m];
            }
        }
    };
    auto storeA32 = [&](int buf) {      // swizzled ds_write (matches read XOR)
        if constexpr (A_F32KM) {
            int m = tid & 63, ks = tid >> 6;
            int ksw = (ks ^ ((m >> 1) & 3)) * 8;
            uint4 h;
            h.x = pk2h(va[0], va[1]);
            h.y = pk2h(va[2], va[3]);
            h.z = pk2h(va[4], va[5]);
            h.w = pk2h(va[6], va[7]);
            *(uint4*)&Ah[buf][m][ksw] = h;
        }
    };
    auto stageA = [&](int kk, int buf) {
        if constexpr (!A_F32KM) {
            const __half* src = Ah_g + (long)b * strideAb +
                                (long)(m0 + w * 16 + gsub) * K + kk + kc * 8;
            gload_lds16(src, &Ah[buf][w * 16][0]);
        }
    };
    auto stageB = [&](int kk, int buf) {
        #pragma unroll
        for (int p = 0; p < BCH; ++p) {
            int ch = w * BCH + p;       // 16-row chunk index
            const __half* src = Bh_g + (long)(n0 + ch * 16 + gsub) * K + kk + kc * 8;
            gload_lds16(src, &Bh[buf][ch * 16][0]);
        }
    };

    loadA32(0);
    stageA(0, 0); stageB(0, 0);
    storeA32(0);
    __syncthreads();                    // drains vmcnt -> gloads landed
    int cur = 0;
    for (int kk = 0; kk < K; kk += 32) {
        const bool more = (kk + 32 < K);
        if (more) {
            loadA32(kk + 32);
            stageA(kk + 32, cur ^ 1);   // async, direct to LDS buf^1
            stageB(kk + 32, cur ^ 1);
        }
        f16x8 bh[NT];
        #pragma unroll
        for (int nt = 0; nt < NT; ++nt)
            bh[nt] = *(const f16x8*)&Bh[cur][wc*NT*16 + nt*16 + lrow][swc];
        #pragma unroll
        for (int mt = 0; mt < MT; ++mt) {
            f16x8 ah = *(const f16x8*)&Ah[cur][wr*MT*16 + mt*16 + lrow][swc];
            #pragma unroll
            for (int nt = 0; nt < NT; ++nt)
                acc[mt][nt] = __builtin_amdgcn_mfma_f32_16x16x32_f16(ah, bh[nt], acc[mt][nt], 0, 0, 0);
        }
        if (more) {
            storeA32(cur ^ 1);
            __syncthreads();            // ONE barrier per k-iter (r0 schedule)
            cur ^= 1;
        }
    }
    // epilogue: C/D col=lane&15, row=(lane>>4)*4+reg
    #pragma unroll
    for (int mt = 0; mt < MT; ++mt) {
        #pragma unroll
        for (int r4 = 0; r4 < 4; ++r4) {
            int m = m0 + wr*MT*16 + mt * 16 + loct * 4 + r4;
            long rowb = (long)b * M + m;
            #pragma unroll
            for (int nt = 0; nt < NT; ++nt) {
                int n = n0 + wc*NT*16 + nt * 16 + lrow;
                float v = acc[mt][nt][r4];
                if constexpr (EPI == HEPI_XP) {
                    Oh0[rowb * N + n] = __float2half(v + bias[n]);
                } else if constexpr (EPI == HEPI_UZ) {
                    if (n < DIN) Oh0[rowb * DIN + n] = __float2half(v);
                    else         Oh1[rowb * DIN + (n - DIN)] = __float2half(v);
                } else {
                    O0[rowb * N + n] = v;
                }
            }
        }
    }
}

#define LDK 40
// ====== old reg-staged hgemm (LDK=40): kept ONLY for D34 (needs OOB zero-guard) ===
template<int EPI, int NT>
__global__ __launch_bounds__(256)
void hgemm(const __half* __restrict__ Ah_g, const __half* __restrict__ Bh_g,
           float* __restrict__ O0, float* __restrict__ Ob, float* __restrict__ Oc,
           int M, int N, int K, long strideAb, int nBlk)
{
    constexpr int BM = 64, MT = 2;
    constexpr int BN = 2 * NT * 16;
    constexpr int BSEG = BN / 64;
    __shared__ __align__(16) _Float16 Ah[2][BM][LDK];
    __shared__ __align__(16) _Float16 Bh[2][BN][LDK];
    const int mBlk = M / BM;
    const int bid = blockIdx.x;
    const int r = bid & 7, q = bid >> 3;
    const int ni = q % nBlk;
    const int mg = (q / nBlk) * 8 + r;
    const int b = mg / mBlk, m_idx = mg - b * mBlk;
    const int n0 = ni * BN, m0 = m_idx * BM;
    const int tid  = threadIdx.x;
    const int lane = tid & 63;
    const int w    = tid >> 6;
    const int wr   = w >> 1, wc = w & 1;
    const int lrow = lane & 15;
    const int loct = lane >> 4;

    f32x4 acc[MT][NT];
    #pragma unroll
    for (int i = 0; i < MT; ++i)
        #pragma unroll
        for (int j = 0; j < NT; ++j)
            acc[i][j] = (f32x4){0.f, 0.f, 0.f, 0.f};

    const int sOct = tid & 3, sRow = tid >> 2;
    uint4 pa, pb[BSEG];

    auto loadA = [&](int kk) {
        pa = *(const uint4*)(Ah_g + (long)b * strideAb +
                             (long)(m0 + sRow) * K + kk + sOct * 8);
    };
    auto loadB = [&](int kk) {
        #pragma unroll
        for (int p = 0; p < BSEG; ++p) {
            int ng = n0 + sRow + p * 64;
            if (ng >= N) pb[p] = make_uint4(0, 0, 0, 0);
            else pb[p] = *(const uint4*)(Bh_g + (long)ng * K + kk + sOct * 8);
        }
    };
    auto storeAB = [&](int buf) {
        *(uint4*)&Ah[buf][sRow][sOct * 8] = pa;
        #pragma unroll
        for (int p = 0; p < BSEG; ++p)
            *(uint4*)&Bh[buf][sRow + p * 64][sOct * 8] = pb[p];
    };

    loadA(0); loadB(0);
    storeAB(0);
    __syncthreads();
    int cur = 0;
    for (int kk = 0; kk < K; kk += 32) {
        const bool more = (kk + 32 < K);
        if (more) { loadA(kk + 32); loadB(kk + 32); }
        f16x8 bh[NT];
        #pragma unroll
        for (int nt = 0; nt < NT; ++nt)
            bh[nt] = *(const f16x8*)&Bh[cur][wc*NT*16 + nt*16 + lrow][loct*8];
        #pragma unroll
        for (int mt = 0; mt < MT; ++mt) {
            f16x8 ah = *(const f16x8*)&Ah[cur][wr*MT*16 + mt*16 + lrow][loct*8];
            #pragma unroll
            for (int nt = 0; nt < NT; ++nt)
                acc[mt][nt] = __builtin_amdgcn_mfma_f32_16x16x32_f16(ah, bh[nt], acc[mt][nt], 0, 0, 0);
        }
        if (more) {
            storeAB(cur ^ 1);
            __syncthreads();
            cur ^= 1;
        }
    }
    #pragma unroll
    for (int mt = 0; mt < MT; ++mt) {
        #pragma unroll
        for (int r4 = 0; r4 < 4; ++r4) {
            int m = m0 + wr*MT*16 + mt * 16 + loct * 4 + r4;
            long rowb = (long)b * M + m;
            #pragma unroll
            for (int nt = 0; nt < NT; ++nt) {
                int n = n0 + wc*NT*16 + nt * 16 + lrow;
                float v = acc[mt][nt][r4];
                if (n < DTR)           O0[rowb * DTR + n] = v;
                else if (n < 2 * DTR)  Ob[rowb * 16 + (n - DTR)] = v;
                else if (n < 48)       Oc[rowb * 16 + (n - 32)] = v;
            }
        }
    }
}

// ---------------- weight prep: fp16 casts ---------
#define SZ_WP  131072
#define SZ_WIN 262144
#define SZ_WO  131072
#define SZ_WC  24576
__global__ __launch_bounds__(256)
void pack_all(const float* __restrict__ Wp, const float* __restrict__ Win,
              const float* __restrict__ Wout, const float* __restrict__ Wx,
              __half* __restrict__ wph, __half* __restrict__ winh,
              __half* __restrict__ woh, __half* __restrict__ wch)
{
    int i = blockIdx.x * 256 + threadIdx.x;
    if (i < SZ_WP) { wph[i] = __float2half(Wp[i]); return; }
    i -= SZ_WP;
    if (i < SZ_WIN) { winh[i] = __float2half(Win[i]); return; }
    i -= SZ_WIN;
    if (i < SZ_WO) { woh[i] = __float2half(Wout[i]); return; }
    i -= SZ_WO;
    if (i < SZ_WC) wch[i] = __float2half(Wx[i]);   // (48, 512) row-major
}

// ------- depthwise causal conv (k=4) + silu: VECTORIZED 8 d's/thread (G13) -------
__global__ __launch_bounds__(256)
void conv_silu_kernel(const __half* __restrict__ u_pre, const float* __restrict__ cw,
                      const float* __restrict__ cb, __half* __restrict__ u)
{
    long gid = (long)blockIdx.x * 256 + threadIdx.x;   // NLD/8 threads
    const int dv = (int)(gid & 63);                    // d0 = dv*8
    const long bl = gid >> 6;                          // b*L + l
    const int l = (int)(bl & (L - 1));
    const long brow = bl - l;
    const int d0 = dv * 8;

    float acc[8];
    {
        float4 c0 = *(const float4*)&cb[d0];
        float4 c1 = *(const float4*)&cb[d0 + 4];
        acc[0]=c0.x; acc[1]=c0.y; acc[2]=c0.z; acc[3]=c0.w;
        acc[4]=c1.x; acc[5]=c1.y; acc[6]=c1.z; acc[7]=c1.w;
    }
    float4 wrow[8];                                    // cw rows (hot 8KB in L2)
    #pragma unroll
    for (int e = 0; e < 8; ++e) wrow[e] = *(const float4*)&cw[(d0 + e) * 4];

    #pragma unroll
    for (int j = 0; j < 4; ++j) {
        int li = l - 3 + j;                            // wave-uniform branch
        if (li >= 0) {
            uint4 raw = *(const uint4*)(u_pre + (brow + li) * DIN + d0);
            const __half2* h2 = (const __half2*)&raw;
            #pragma unroll
            for (int e = 0; e < 4; ++e) {
                float2 f = __half22float2(h2[e]);
                float w0 = (j == 0) ? wrow[2*e].x : (j == 1) ? wrow[2*e].y
                         : (j == 2) ? wrow[2*e].z : wrow[2*e].w;
                float w1 = (j == 0) ? wrow[2*e+1].x : (j == 1) ? wrow[2*e+1].y
                         : (j == 2) ? wrow[2*e+1].z : wrow[2*e+1].w;
                acc[2*e]   = fmaf(f.x, w0, acc[2*e]);
                acc[2*e+1] = fmaf(f.y, w1, acc[2*e+1]);
            }
        }
    }
    uint4 st;
    st.x = pk2h(silu_f(acc[0]), silu_f(acc[1]));
    st.y = pk2h(silu_f(acc[2]), silu_f(acc[3]));
    st.z = pk2h(silu_f(acc[4]), silu_f(acc[5]));
    st.w = pk2h(silu_f(acc[6]), silu_f(acc[7]));
    *(uint4*)(u + bl * DIN + d0) = st;
}

// ---------------- chunked parallel selective scan, d-per-lane ----------------
// r15: phase3 Dl reads batched in groups of 8 (phase2 pattern) to hide L2 latency.
#define NC 128
#define LC (L / NC)

__device__ __forceinline__ f32x2 fma2(f32x2 a, f32x2 b, f32x2 c) {
    return __builtin_elementwise_fma(a, b, c);
}
__device__ __forceinline__ void ld4s(const float* p, f32x2& lo, f32x2& hi) {
    f32x4 v = *(const f32x4*)p;
    lo = __builtin_shufflevector(v, v, 0, 1);
    hi = __builtin_shufflevector(v, v, 2, 3);
}

#define LDA2(qi, lo, hi) { \
    float4 v_ = *(const float4*)&A_log[d * DSTATE + (qi) * 4]; \
    lo = (f32x2){-__expf(v_.x) * LOG2E, -__expf(v_.y) * LOG2E}; \
    hi = (f32x2){-__expf(v_.z) * LOG2E, -__expf(v_.w) * LOG2E}; }

#define LDW2(qi, lo, hi) { \
    float4 v_ = *(const float4*)&Wdt[d * DTR + (qi) * 4]; \
    lo = (f32x2){v_.x, v_.y}; hi = (f32x2){v_.z, v_.w}; }

__global__ __launch_bounds__(256)
void scan_phase1(const float* __restrict__ dtA, const __half* __restrict__ u,
                 const float* __restrict__ Bm, const float* __restrict__ A_log,
                 const float* __restrict__ Wdt, const float* __restrict__ bdt,
                 float* __restrict__ Xc, float* __restrict__ DS,
                 float* __restrict__ Dl)
{
    __shared__ float sB[LC][DSTATE];
    __shared__ float sDt[LC][DTR];
    __shared__ __half sU[LC][256];
    const int gd = blockIdx.x & 1;
    const int c  = (blockIdx.x >> 1) & (NC - 1);
    const int b  = blockIdx.x >> 8;
    const int tid = threadIdx.x;
    const int d  = gd * 256 + tid;
    const int t0 = c * LC;
    f32x2 A20, A21, A22, A23, A24, A25, A26, A27;
    LDA2(0, A20, A21) LDA2(1, A22, A23) LDA2(2, A24, A25) LDA2(3, A26, A27)
    f32x2 W0, W1, W2, W3, W4, W5, W6, W7;
    LDW2(0, W0, W1) LDW2(1, W2, W3) LDW2(2, W4, W5) LDW2(3, W6, W7)
    const float bd = bdt[d];
    {
        const __half* ub = u + ((long)b * L + t0) * DIN + gd * 256;
        #pragma unroll
        for (int j = 0; j < 4; ++j) {
            int i = tid + j * 256;            // 1024 float4s = 32 rows x 32
            int t = i >> 5, col = (i & 31) * 8;
            *(float4*)&sU[t][col] = *(const float4*)&ub[(long)t * DIN + col];
        }
        if (tid < 128) {
            const float* Bb = Bm  + ((long)b * L + t0) * DSTATE;
            const float* Db = dtA + ((long)b * L + t0) * DTR;
            *(float4*)&((float*)sB)[tid * 4]  = *(const float4*)&Bb[tid * 4];
            *(float4*)&((float*)sDt)[tid * 4] = *(const float4*)&Db[tid * 4];
        }
    }
    __syncthreads();
    f32x2 X20 = {0,0}, X21 = {0,0}, X22 = {0,0}, X23 = {0,0};
    f32x2 X24 = {0,0}, X25 = {0,0}, X26 = {0,0}, X27 = {0,0};
    float dsum = 0.f;
    const long gbase = ((long)b * L + t0) * DIN + d;
    #pragma unroll 2
    for (int t = 0; t < LC; ++t) {
        f32x2 q0, q1, q2, q3, q4, q5, q6, q7;
        ld4s(&sDt[t][0],  q0, q1);
        ld4s(&sDt[t][4],  q2, q3);
        ld4s(&sDt[t][8],  q4, q5);
        ld4s(&sDt[t][12], q6, q7);
        f32x2 dpA = q0 * W0, dpB = q1 * W1;
        dpA = fma2(q2, W2, dpA); dpB = fma2(q3, W3, dpB);
        dpA = fma2(q4, W4, dpA); dpB = fma2(q5, W5, dpB);
        dpA = fma2(q6, W6, dpA); dpB = fma2(q7, W7, dpB);
        float dlt = softplus_fast(((dpA.x + dpA.y) + (dpB.x + dpB.y)) + bd);
        Dl[gbase + (long)t * DIN] = dlt;          // fp32 handoff to phase3
        dsum += dlt;
        float du = dlt * __half2float(sU[t][tid]);
        f32x2 du2  = (f32x2){du, du};
        f32x2 dlt2 = (f32x2){dlt, dlt};
        f32x2 b0, b1, b2, b3, b4, b5, b6, b7;
        ld4s(&sB[t][0],  b0, b1);
        ld4s(&sB[t][4],  b2, b3);
        ld4s(&sB[t][8],  b4, b5);
        ld4s(&sB[t][12], b6, b7);
#define P1K(k) { f32x2 tt = dlt2 * A2##k; f32x2 a_; \
        a_.x = EXP2(tt.x); a_.y = EXP2(tt.y); \
        X2##k = fma2(a_, X2##k, du2 * b##k); }
        P1K(0) P1K(1) P1K(2) P1K(3) P1K(4) P1K(5) P1K(6) P1K(7)
#undef P1K
    }
    long o = (((long)b * NC + c) * DIN + d) * DSTATE;
    *(float4*)&Xc[o + 0]  = make_float4(X20.x, X20.y, X21.x, X21.y);
    *(float4*)&Xc[o + 4]  = make_float4(X22.x, X22.y, X23.x, X23.y);
    *(float4*)&Xc[o + 8]  = make_float4(X24.x, X24.y, X25.x, X25.y);
    *(float4*)&Xc[o + 12] = make_float4(X26.x, X26.y, X27.x, X27.y);
    DS[((long)b * NC + c) * DIN + d] = dsum;
}

// cross-chunk scan: 32768 independent series; pure-ILP kernel.
__global__ __launch_bounds__(256)
void scan_phase2(const float* __restrict__ Xc, const float* __restrict__ DS,
                 const float* __restrict__ A_log, float* __restrict__ Hout)
{
    int lane = blockIdx.x * 256 + threadIdx.x;   // 32768 total
    int b = lane >> 13;
    int rem = lane & 8191;                       // d*16 + s
    int d = rem >> 4;
    const float Ar = -__expf(A_log[rem]) * LOG2E;
    const long cs = (long)DIN * DSTATE;
    const long xb = (long)b * NC * cs + rem;
    const long db = (long)b * NC * DIN + d;
    float h = 0.f;
    float xc_[8], ts_[8], nx_[8], nt_[8];
    auto ldx = [&](int c) { return Xc[xb + (long)c * cs]; };
    auto ldt = [&](int c) { return DS[db + (long)c * DIN]; };
    #pragma unroll
    for (int j = 0; j < 8; ++j) { xc_[j] = ldx(j);     ts_[j] = ldt(j); }
    #pragma unroll
    for (int j = 0; j < 8; ++j) { nx_[j] = ldx(8 + j); nt_[j] = ldt(8 + j); }
    for (int c = 0; c < NC; c += 8) {
        #pragma unroll
        for (int j = 0; j < 8; ++j) {
            Hout[xb + (long)(c + j) * cs] = h;
            h = fmaf(EXP2(ts_[j] * Ar), h, xc_[j]);
        }
        #pragma unroll
        for (int j = 0; j < 8; ++j) { xc_[j] = nx_[j]; ts_[j] = nt_[j]; }
        if (c + 16 < NC) {
            #pragma unroll
            for (int j = 0; j < 8; ++j) {
                nx_[j] = ldx(c + 16 + j);
                nt_[j] = ldt(c + 16 + j);
            }
        }
    }
}

__global__ __launch_bounds__(256)
void scan_phase3(const float* __restrict__ Dl, const __half* __restrict__ u,
                 const float* __restrict__ Bm, const float* __restrict__ Cm,
                 const __half* __restrict__ z, const float* __restrict__ A_log,
                 const float* __restrict__ Dp, const float* __restrict__ Hinit,
                 __half* __restrict__ y2h)
{
    __shared__ float sB[LC][DSTATE], sC[LC][DSTATE];
    __shared__ __half sU[LC][256];
    __shared__ __half sZ[LC][256];
    const int gd = blockIdx.x & 1;
    const int c  = (blockIdx.x >> 1) & (NC - 1);
    const int b  = blockIdx.x >> 8;
    const int tid = threadIdx.x;
    const int d  = gd * 256 + tid;
    const int t0 = c * LC;
    f32x2 A20, A21, A22, A23, A24, A25, A26, A27;
    LDA2(0, A20, A21) LDA2(1, A22, A23) LDA2(2, A24, A25) LDA2(3, A26, A27)
    {
        const __half* ub = u  + ((long)b * L + t0) * DIN + gd * 256;
        const __half* zb = z  + ((long)b * L + t0) * DIN + gd * 256;
        #pragma unroll
        for (int j = 0; j < 4; ++j) {
            int i = tid + j * 256;
            int t = i >> 5, col = (i & 31) * 8;
            *(float4*)&sU[t][col] = *(const float4*)&ub[(long)t * DIN + col];
            *(float4*)&sZ[t][col] = *(const float4*)&zb[(long)t * DIN + col];
        }
        if (tid < 128) {
            const float* Bb = Bm  + ((long)b * L + t0) * DSTATE;
            const float* Cb = Cm  + ((long)b * L + t0) * DSTATE;
            *(float4*)&((float*)sB)[tid * 4]  = *(const float4*)&Bb[tid * 4];
            *(float4*)&((float*)sC)[tid * 4]  = *(const float4*)&Cb[tid * 4];
        }
    }
    f32x2 h20, h21, h22, h23, h24, h25, h26, h27;
    {
        long o = (((long)b * NC + c) * DIN + d) * DSTATE;
        ld4s(&Hinit[o + 0],  h20, h21);
        ld4s(&Hinit[o + 4],  h22, h23);
        ld4s(&Hinit[o + 8],  h24, h25);
        ld4s(&Hinit[o + 12], h26, h27);
    }
    const float Dval = Dp[d];
    const long gbase = ((long)b * L + t0) * DIN + d;
    __syncthreads();
    // Dl batched prefetch: groups of 8 t's, next group in flight during compute.
    float dl_[8], ndl_[8];
    #pragma unroll
    for (int j = 0; j < 8; ++j) dl_[j]  = Dl[gbase + (long)j * DIN];
    #pragma unroll
    for (int j = 0; j < 8; ++j) ndl_[j] = Dl[gbase + (long)(8 + j) * DIN];
    for (int g = 0; g < LC; g += 8) {
        #pragma unroll
        for (int j = 0; j < 8; ++j) {
            const int t = g + j;
            float dlt = dl_[j];
            float uu = __half2float(sU[t][tid]);
            float zz = __half2float(sZ[t][tid]);
            float du = dlt * uu;
            f32x2 du2  = (f32x2){du, du};
            f32x2 dlt2 = (f32x2){dlt, dlt};
            f32x2 b0, b1, b2, b3, b4, b5, b6, b7;
            ld4s(&sB[t][0],  b0, b1);
            ld4s(&sB[t][4],  b2, b3);
            ld4s(&sB[t][8],  b4, b5);
            ld4s(&sB[t][12], b6, b7);
            f32x2 c0, c1, c2, c3, c4, c5, c6, c7;
            ld4s(&sC[t][0],  c0, c1);
            ld4s(&sC[t][4],  c2, c3);
            ld4s(&sC[t][8],  c4, c5);
            ld4s(&sC[t][12], c6, c7);
            f32x2 y2a = {0,0}, y2b = {0,0}, y2c = {0,0}, y2d = {0,0};
#define P3K(k, yacc) { f32x2 tt = dlt2 * A2##k; f32x2 a_; \
            a_.x = EXP2(tt.x); a_.y = EXP2(tt.y); \
            h2##k = fma2(h2##k, a_, du2 * b##k); \
            yacc = fma2(h2##k, c##k, yacc); }
            P3K(0, y2a) P3K(1, y2b) P3K(2, y2c) P3K(3, y2d)
            P3K(4, y2a) P3K(5, y2b) P3K(6, y2c) P3K(7, y2d)
#undef P3K
            f32x2 ys = (y2a + y2b) + (y2c + y2d);
            float y = ys.x + ys.y;
            y2h[gbase + (long)t * DIN] = __float2half((y + uu * Dval) * silu_f(zz));
        }
        #pragma unroll
        for (int j = 0; j < 8; ++j) dl_[j] = ndl_[j];
        if (g + 16 < LC) {
            #pragma unroll
            for (int j = 0; j < 8; ++j)
                ndl_[j] = Dl[gbase + (long)(g + 16 + j) * DIN];
        }
    }
}

// ---------------- LayerNorm over C + transpose to (B,C,L) ----------------
__global__ __launch_bounds__(256)
void ln_kernel(const float* __restrict__ X, const float* __restrict__ gamma,
               const float* __restrict__ beta, float* __restrict__ out)
{
    __shared__ float tile[32][257];
    __shared__ float sMu[32], sRs[32];
    const int l0 = blockIdx.x * 32;
    const int b  = blockIdx.y;
    const int tid = threadIdx.x;
    for (int i = tid; i < 32 * 256; i += 256) {
        int l = i >> 8, c = i & 255;
        tile[l][c] = X[((long)b * L + l0 + l) * CDIM + c];
    }
    __syncthreads();
    {
        int l = tid >> 3, sub = tid & 7;
        float s1 = 0.f, s2 = 0.f;
        for (int c = sub * 32; c < sub * 32 + 32; ++c) {
            float v = tile[l][c];
            s1 += v; s2 += v * v;
        }
        s1 += __shfl_xor(s1, 1); s2 += __shfl_xor(s2, 1);
        s1 += __shfl_xor(s1, 2); s2 += __shfl_xor(s2, 2);
        s1 += __shfl_xor(s1, 4); s2 += __shfl_xor(s2, 4);
        if (sub == 0) {
            float mu = s1 * (1.f / 256.f);
            float var = s2 * (1.f / 256.f) - mu * mu;
            sMu[l] = mu;
            sRs[l] = rsqrtf(var + 1e-5f);
        }
    }
    __syncthreads();
    for (int i = tid; i < 32 * 256; i += 256) {
        int ll = i & 31, c = i >> 5;
        float v = (tile[ll][c] - sMu[ll]) * sRs[ll] * gamma[c] + beta[c];
        out[((long)b * CDIM + c) * L + l0 + ll] = v;
    }
}

extern "C" void kernel_launch(void* const* d_in, const int* in_sizes, int n_in,
                              void* d_out, int out_size, void* d_ws, size_t ws_size,
                              hipStream_t stream)
{
    const float* sp   = (const float*)d_in[0];
    const float* fq   = (const float*)d_in[1];
    const float* Wp   = (const float*)d_in[2];
    const float* bp   = (const float*)d_in[3];
    const float* Win  = (const float*)d_in[4];
    const float* cw   = (const float*)d_in[5];
    const float* cb   = (const float*)d_in[6];
    const float* Wx   = (const float*)d_in[7];
    const float* Wdt  = (const float*)d_in[8];
    const float* bdt  = (const float*)d_in[9];
    const float* Alog = (const float*)d_in[10];
    const float* Dp   = (const float*)d_in[11];
    const float* Wout = (const float*)d_in[12];
    const float* gam  = (const float*)d_in[13];
    const float* bet  = (const float*)d_in[14];
    float* out = (float*)d_out;
    float* ws  = (float*)d_ws;

    const size_t NLD = (size_t)BATCH * L * DIN;   // 8.39M
    const size_t NLC = (size_t)BATCH * L * CDIM;  // 4.19M

    size_t off = 0;
    __half* u16   = (__half*)(ws + off); off += NLD / 2;  // pre-conv u
    __half* u16c  = (__half*)(ws + off); off += NLD / 2;  // post-conv silu(u)
    __half* z16   = (__half*)(ws + off); off += NLD / 2;
    __half* y16   = (__half*)(ws + off); off += NLD / 2;
    __half* xp16  = (__half*)(ws + off); off += NLC / 2;
    float*  xmix  = ws + off; off += NLC;
    float*  dtA   = ws + off; off += (size_t)BATCH * L * DTR;
    float*  Dl    = ws + off; off += NLD;                 // fp32 delta handoff
    __half* wph   = (__half*)(ws + off); off += SZ_WP / 2;
    __half* winh  = (__half*)(ws + off); off += SZ_WIN / 2;
    __half* woh   = (__half*)(ws + off); off += SZ_WO / 2;
    __half* wch   = (__half*)(ws + off); off += SZ_WC / 2;
    float*  Bmb   = ws + off; off += (size_t)BATCH * L * DSTATE;
    float*  Cmb   = ws + off; off += (size_t)BATCH * L * DSTATE;
    float*  Xc    = ws + off; off += (size_t)BATCH * NC * DIN * DSTATE;
    float*  DS    = ws + off; off += (size_t)BATCH * NC * DIN;
    float*  Hout  = ws + off; off += (size_t)BATCH * NC * DIN * DSTATE;

    dim3 blk(256);
    pack_all<<<dim3((SZ_WP + SZ_WIN + SZ_WO + SZ_WC) / 256), blk, 0, stream>>>(
        Wp, Win, Wout, Wx, wph, winh, woh, wch);

    // GEMM1: x_proj = x_cat @ Wp^T + bp  (A fp32 K-major reg-staged; B gload_lds)
    hgemm_g<HEPI_XP, true, 2><<<dim3(BATCH * (L/64) * 4), blk, 0, stream>>>(
        sp, fq, nullptr, wph, bp, nullptr, xp16, nullptr,
        L, CDIM, 2 * CDIM, CDIM, (long)CDIM * L, 4);
    // GEMM2: xz = x_proj @ Win^T -> u16 / z16  (full gload_lds staging)
    hgemm_g<HEPI_UZ, false, 4><<<dim3(BATCH * (L/64) * 8), blk, 0, stream>>>(
        nullptr, nullptr, xp16, winh, nullptr, nullptr, u16, z16,
        L, 2 * DIN, CDIM, 1 << 30, (long)L * CDIM, 8);

    conv_silu_kernel<<<dim3((int)(NLD / 8 / 256)), blk, 0, stream>>>(u16, cw, cb, u16c);
    // D34 rank-16: dbc = u @ Wx^T (N=48: dt|Bm|Cm) -- old kernel (OOB guard)
    hgemm<HEPI_D34, 2><<<dim3(BATCH * (L/64) * 1), blk, 0, stream>>>(
        u16c, wch, dtA, Bmb, Cmb, L, 48, DIN, (long)L * DIN, 1);

    scan_phase1<<<dim3(BATCH * NC * 2), blk, 0, stream>>>(
        dtA, u16c, Bmb, Alog, Wdt, bdt, Xc, DS, Dl);
    scan_phase2<<<dim3(BATCH * DIN * DSTATE / 256), blk, 0, stream>>>(Xc, DS, Alog, Hout);
    scan_phase3<<<dim3(BATCH * NC * 2), blk, 0, stream>>>(
        Dl, u16c, Bmb, Cmb, z16, Alog, Dp, Hout, y16);

    // GEMM5: x_mixed = y2 @ Wout^T  (full gload_lds staging)
    hgemm_g<HEPI_F32, false, 2><<<dim3(BATCH * (L/64) * 4), blk, 0, stream>>>(
        nullptr, nullptr, y16, woh, nullptr, xmix, nullptr, nullptr,
        L, CDIM, DIN, 1 << 30, (long)L * DIN, 4);
    ln_kernel<<<dim3(L / 32, BATCH), blk, 0, stream>>>(xmix, gam, bet, out);
}